// Round 6
// baseline (656.000 us; speedup 1.0000x reference)
//
#include <hip/hip_runtime.h>

#define NN 50000
#define NE 800000

typedef _Float16 half8 __attribute__((ext_vector_type(8)));
typedef _Float16 half4 __attribute__((ext_vector_type(4)));
typedef float f32x4 __attribute__((ext_vector_type(4)));

// ws layout (float offsets)
static const size_t XOFF   = 0;          // x      [50000*64] f32
static const size_t POFF   = 3200000;    // P      [50000*128] f16
static const size_t QOFF   = 6400000;    // Q      [50000*128] f16
static const size_t N1OFF  = 9600000;    // nfoc1  [50000*64] f32
static const size_t N2OFF  = 12800000;   // nfoc2  [50000*64] u32 (monotonic-encoded)
static const size_t W2TOFF = 16000000;   // w2t    [128 cols][128 k] f16 (col-major)
static const size_t W2GOFF = 16008192;   // w2gate [128] f32
static const size_t CNTOFF = 16008320;   // counts [50000] u32
static const size_t CUROFF = 16058320;   // cursor [50000] u32
static const size_t PARTOFF= 16108320;   // partial[256] u32
static const size_t PERMOFF= 16108576;   // perm   [800000] u32

__device__ __forceinline__ unsigned fenc(float f){
  unsigned b = __float_as_uint(f);
  return (b & 0x80000000u) ? ~b : (b | 0x80000000u);
}
__device__ __forceinline__ float fdec(unsigned u){
  return (u & 0x80000000u) ? __uint_as_float(u & 0x7fffffffu) : __uint_as_float(~u);
}
__device__ __forceinline__ float lrelu(float v){ return v > 0.f ? v : 0.2f * v; }

// 64x64 tile GEMM: acc[4][4] = bias + sIn(64x64, pad65) @ W(64x64 row-major)
__device__ __forceinline__ void gemm64(const float (*sIn)[65], const float* __restrict__ W,
                                       const float* __restrict__ bias, int t, float acc[4][4])
{
  const int c0 = (t & 15) * 4, r0 = (t >> 4) * 4;
  const float4 b4 = *(const float4*)&bias[c0];
  #pragma unroll
  for (int j = 0; j < 4; ++j){ acc[j][0]=b4.x; acc[j][1]=b4.y; acc[j][2]=b4.z; acc[j][3]=b4.w; }
  #pragma unroll 4
  for (int k = 0; k < 64; ++k){
    const float4 w4 = *(const float4*)&W[k*64 + c0];
    #pragma unroll
    for (int j = 0; j < 4; ++j){
      const float a = sIn[r0+j][k];
      acc[j][0] = fmaf(a, w4.x, acc[j][0]);
      acc[j][1] = fmaf(a, w4.y, acc[j][1]);
      acc[j][2] = fmaf(a, w4.z, acc[j][2]);
      acc[j][3] = fmaf(a, w4.w, acc[j][3]);
    }
  }
}

// blocks 0..64: msg_w2 [128][129] -> w2t f16 col-major + w2gate f32.
// blocks 65+: histogram of dst (counts pre-zeroed by memset).
__global__ __launch_bounds__(256) void prep_k(const float* __restrict__ w2,
                                              _Float16* __restrict__ w2t,
                                              float* __restrict__ w2g,
                                              const int* __restrict__ dst,
                                              unsigned* __restrict__ counts)
{
  const int b = blockIdx.x;
  if (b < 65){
    int i = b * 256 + threadIdx.x;
    if (i < 16384){
      int c = i >> 7, k = i & 127;
      w2t[i] = (_Float16)w2[k*129 + 1 + c];
    } else if (i < 16512){
      int k = i - 16384;
      w2g[k] = w2[k*129];
    }
  } else {
    int e = (b - 65) * 256 + threadIdx.x;
    if (e < NE) atomicAdd(&counts[dst[e]], 1u);
  }
}

// per-block sums of counts -> partial[196]
__global__ __launch_bounds__(256) void scanA(const unsigned* __restrict__ counts,
                                             unsigned* __restrict__ partial)
{
  __shared__ unsigned s[256];
  const int t = threadIdx.x;
  const int idx = blockIdx.x * 256 + t;
  s[t] = (idx < NN) ? counts[idx] : 0u;
  __syncthreads();
  for (int d = 128; d > 0; d >>= 1){
    if (t < d) s[t] += s[t + d];
    __syncthreads();
  }
  if (t == 0) partial[blockIdx.x] = s[0];
}

// exclusive scan of partial[196] in place (256 padded)
__global__ __launch_bounds__(256) void scanB(unsigned* __restrict__ partial, int nb)
{
  __shared__ unsigned s[256];
  const int t = threadIdx.x;
  unsigned v = (t < nb) ? partial[t] : 0u;
  s[t] = v;
  __syncthreads();
  for (int d = 1; d < 256; d <<= 1){
    unsigned u = (t >= d) ? s[t - d] : 0u;
    __syncthreads();
    s[t] += u;
    __syncthreads();
  }
  if (t < nb) partial[t] = s[t] - v;   // exclusive
}

// block-local exclusive scan + global offset -> cursor
__global__ __launch_bounds__(256) void scanC(const unsigned* __restrict__ counts,
                                             const unsigned* __restrict__ partial,
                                             unsigned* __restrict__ cursor)
{
  __shared__ unsigned s[256];
  const int t = threadIdx.x;
  const int idx = blockIdx.x * 256 + t;
  unsigned v = (idx < NN) ? counts[idx] : 0u;
  s[t] = v;
  __syncthreads();
  for (int d = 1; d < 256; d <<= 1){
    unsigned u = (t >= d) ? s[t - d] : 0u;
    __syncthreads();
    s[t] += u;
    __syncthreads();
  }
  if (idx < NN) cursor[idx] = partial[blockIdx.x] + s[t] - v;
}

// slot assignment: perm[slot] = edge id, slots grouped by dst
__global__ __launch_bounds__(256) void assign_k(const int* __restrict__ dst,
                                                unsigned* __restrict__ cursor,
                                                unsigned* __restrict__ perm)
{
  int e = blockIdx.x * 256 + threadIdx.x;
  if (e < NE){
    unsigned slot = atomicAdd(&cursor[dst[e]], 1u);
    perm[slot] = (unsigned)e;
  }
}

// Node-side precompute: x = residual(nf); x1 = x@l1w+b -> out; P/Q = x@W1 halves (f16).
__global__ __launch_bounds__(256) void node_pre(
    const float* __restrict__ nf,
    const float* __restrict__ rw1, const float* __restrict__ rb1,
    const float* __restrict__ rw2, const float* __restrict__ rb2,
    const float* __restrict__ l1w, const float* __restrict__ l1b,
    const float* __restrict__ w1,   // msg_w1 [128][128]
    float* __restrict__ x_out, _Float16* __restrict__ Pp, _Float16* __restrict__ Qp,
    float* __restrict__ out)
{
  __shared__ float sA[64][65];
  __shared__ float sB[64][65];
  const int t = threadIdx.x;
  const int n0 = blockIdx.x * 64;
  const int rr = t >> 4, c4 = (t & 15) * 4;

  #pragma unroll
  for (int i = 0; i < 4; ++i){
    int r = rr + i*16, n = n0 + r;
    float4 v = make_float4(0.f,0.f,0.f,0.f);
    if (n < NN) v = *(const float4*)&nf[n*64 + c4];
    sA[r][c4+0]=v.x; sA[r][c4+1]=v.y; sA[r][c4+2]=v.z; sA[r][c4+3]=v.w;
  }
  __syncthreads();

  float acc[4][4];
  const int c0 = (t & 15) * 4, r0 = (t >> 4) * 4;

  gemm64(sA, rw1, rb1, t, acc);
  #pragma unroll
  for (int j = 0; j < 4; ++j)
    #pragma unroll
    for (int i = 0; i < 4; ++i) sB[r0+j][c0+i] = acc[j][i];
  __syncthreads();

  gemm64(sB, rw2, rb2, t, acc);
  #pragma unroll
  for (int j = 0; j < 4; ++j)
    #pragma unroll
    for (int i = 0; i < 4; ++i) acc[j][i] += sA[r0+j][c0+i];
  __syncthreads();
  #pragma unroll
  for (int j = 0; j < 4; ++j){
    #pragma unroll
    for (int i = 0; i < 4; ++i) sA[r0+j][c0+i] = acc[j][i];
    int n = n0 + r0 + j;
    if (n < NN){
      float4 v = make_float4(acc[j][0],acc[j][1],acc[j][2],acc[j][3]);
      *(float4*)&x_out[n*64 + c0] = v;
    }
  }
  __syncthreads();

  gemm64(sA, l1w, l1b, t, acc);
  #pragma unroll
  for (int j = 0; j < 4; ++j){
    int n = n0 + r0 + j;
    if (n < NN){
      float4 v = make_float4(acc[j][0],acc[j][1],acc[j][2],acc[j][3]);
      *(float4*)&out[n*64 + c0] = v;
    }
  }

  #pragma unroll
  for (int part = 0; part < 2; ++part){
    _Float16* dstp = part ? Qp : Pp;
    const float* Wp = w1 + (size_t)part * 64 * 128;
    for (int ch = 0; ch < 2; ++ch){
      float a2[4][4];
      #pragma unroll
      for (int j = 0; j < 4; ++j)
        #pragma unroll
        for (int i = 0; i < 4; ++i) a2[j][i] = 0.f;
      #pragma unroll 4
      for (int k = 0; k < 64; ++k){
        const float4 w4 = *(const float4*)&Wp[k*128 + ch*64 + c0];
        #pragma unroll
        for (int j = 0; j < 4; ++j){
          const float a = sA[r0+j][k];
          a2[j][0] = fmaf(a, w4.x, a2[j][0]);
          a2[j][1] = fmaf(a, w4.y, a2[j][1]);
          a2[j][2] = fmaf(a, w4.z, a2[j][2]);
          a2[j][3] = fmaf(a, w4.w, a2[j][3]);
        }
      }
      #pragma unroll
      for (int j = 0; j < 4; ++j){
        int n = n0 + r0 + j;
        if (n < NN){
          half4 v;
          #pragma unroll
          for (int i = 0; i < 4; ++i) v[i] = (_Float16)a2[j][i];
          *(half4*)&dstp[(size_t)n*128 + ch*64 + c0] = v;
        }
      }
    }
  }
}

// Edge MLP, fully wave-independent: no LDS, no barriers.
// Each wave = one 16-edge dst-sorted tile. A-frags gathered straight into MFMA layout.
__global__ __launch_bounds__(256) void edge_mlp5(
    const int* __restrict__ src, const int* __restrict__ dst,
    const _Float16* __restrict__ Pp, const _Float16* __restrict__ Qp,
    const float* __restrict__ b1,
    const _Float16* __restrict__ w2t, const float* __restrict__ w2g,
    const float* __restrict__ b2,
    const unsigned* __restrict__ perm,
    float* __restrict__ nfoc1, unsigned* __restrict__ nfoc2)
{
  const int t = threadIdx.x;
  const int lane = t & 63;
  const int wv = t >> 6;
  const int r  = lane & 15;     // edge row within tile (= MFMA A-row, B-col, D-col)
  const int kg = lane >> 4;     // k-group (= MFMA k-slice, D-row-quad)
  const int sl0 = blockIdx.x * 64 + wv * 16;

  const unsigned e = perm[sl0 + r];
  const int s = src[e], d = dst[e];

  // gather A-fragments (mid row r, k-slices) + fused gate partial
  half4 af[8];
  float gp = 0.f;
  const _Float16* prow = &Pp[(size_t)s * 128];
  const _Float16* qrow = &Qp[(size_t)d * 128];
  #pragma unroll
  for (int kt = 0; kt < 8; ++kt){
    const int k0 = kt*16 + kg*4;
    const half4 ph = *(const half4*)&prow[k0];
    const half4 qh = *(const half4*)&qrow[k0];
    const float4 bb = *(const float4*)&b1[k0];
    const float4 wg = *(const float4*)&w2g[k0];
    float v0 = lrelu((float)ph[0] + (float)qh[0] + bb.x);
    float v1 = lrelu((float)ph[1] + (float)qh[1] + bb.y);
    float v2 = lrelu((float)ph[2] + (float)qh[2] + bb.z);
    float v3 = lrelu((float)ph[3] + (float)qh[3] + bb.w);
    gp = fmaf(v0, wg.x, fmaf(v1, wg.y, fmaf(v2, wg.z, fmaf(v3, wg.w, gp))));
    half4 m; m[0]=(_Float16)v0; m[1]=(_Float16)v1; m[2]=(_Float16)v2; m[3]=(_Float16)v3;
    af[kt] = m;
  }
  // full gate for row r (all 4 k-groups)
  gp += __shfl_xor(gp, 16);
  gp += __shfl_xor(gp, 32);
  const float gate = 1.f / (1.f + expf(-(gp + b2[0])));

  // per-quad row metadata (rows kg*4+0..3 of D)
  int   dr[4];
  float gr[4];
  #pragma unroll
  for (int j = 0; j < 4; ++j){
    dr[j] = __shfl(d,    kg*4 + j);
    gr[j] = __shfl(gate, kg*4 + j);
  }
  // dst-sorted tile: uniform iff first == last
  const bool uni = (__shfl(d, 0) == __shfl(d, 15));

  for (int ct = 0; ct < 8; ++ct){
    const int col = ct*16 + r;
    const _Float16* wc = &w2t[(size_t)col * 128 + kg*4];
    f32x4 acc = {0.f, 0.f, 0.f, 0.f};
    #pragma unroll
    for (int kt = 0; kt < 8; ++kt){
      const half4 bf = *(const half4*)&wc[kt*16];
      acc = __builtin_amdgcn_mfma_f32_16x16x16f16(af[kt], bf, acc, 0, 0, 0);
    }
    const float bc = b2[1 + col];
    float val[4];
    #pragma unroll
    for (int j = 0; j < 4; ++j) val[j] = (acc[j] + bc) * gr[j];

    if (uni){
      if (ct < 4){
        float v = val[0] + val[1] + val[2] + val[3];
        v += __shfl_xor(v, 16);
        v += __shfl_xor(v, 32);
        if (lane < 16) unsafeAtomicAdd(&nfoc1[(size_t)d*64 + col], v);
      } else {
        float v = fmaxf(fmaxf(val[0], val[1]), fmaxf(val[2], val[3]));
        v = fmaxf(v, __shfl_xor(v, 16));
        v = fmaxf(v, __shfl_xor(v, 32));
        if (lane < 16) atomicMax(&nfoc2[(size_t)d*64 + (col - 64)], fenc(v));
      }
    } else {
      if (ct < 4){
        float a = val[0]; int cd = dr[0];
        #pragma unroll
        for (int j = 1; j < 4; ++j){
          if (dr[j] == cd) a += val[j];
          else { unsafeAtomicAdd(&nfoc1[(size_t)cd*64 + col], a); cd = dr[j]; a = val[j]; }
        }
        unsafeAtomicAdd(&nfoc1[(size_t)cd*64 + col], a);
      } else {
        float a = val[0]; int cd = dr[0];
        #pragma unroll
        for (int j = 1; j < 4; ++j){
          if (dr[j] == cd) a = fmaxf(a, val[j]);
          else { atomicMax(&nfoc2[(size_t)cd*64 + (col - 64)], fenc(a)); cd = dr[j]; a = val[j]; }
        }
        atomicMax(&nfoc2[(size_t)cd*64 + (col - 64)], fenc(a));
      }
    }
  }
}

// Node-side post: new_x = concat(x,nfoc1,dec(nfoc2))@red_w+red_b; out += new_x@l2w+l2b
__global__ __launch_bounds__(256) void node_post(
    const float* __restrict__ x, const float* __restrict__ nfoc1,
    const unsigned* __restrict__ nfoc2, const unsigned* __restrict__ counts,
    const float* __restrict__ redw, const float* __restrict__ redb,
    const float* __restrict__ l2w, const float* __restrict__ l2b,
    float* __restrict__ out)
{
  __shared__ float sC[64][197];
  __shared__ float sN[64][65];
  const int t = threadIdx.x;
  const int n0 = blockIdx.x * 64;
  const int rr = t >> 4, c4 = (t & 15) * 4;

  #pragma unroll
  for (int i = 0; i < 4; ++i){
    int r = rr + i*16, n = n0 + r;
    float4 xv = make_float4(0,0,0,0), f1 = make_float4(0,0,0,0);
    uint4 f2 = make_uint4(0,0,0,0);
    bool has = false;
    if (n < NN){
      xv = *(const float4*)&x[(size_t)n*64 + c4];
      f1 = *(const float4*)&nfoc1[(size_t)n*64 + c4];
      f2 = *(const uint4*)&nfoc2[(size_t)n*64 + c4];
      has = counts[n] > 0u;
    }
    sC[r][c4+0]=xv.x; sC[r][c4+1]=xv.y; sC[r][c4+2]=xv.z; sC[r][c4+3]=xv.w;
    sC[r][64+c4+0]=f1.x; sC[r][64+c4+1]=f1.y; sC[r][64+c4+2]=f1.z; sC[r][64+c4+3]=f1.w;
    sC[r][128+c4+0] = has ? fdec(f2.x) : 0.f;
    sC[r][128+c4+1] = has ? fdec(f2.y) : 0.f;
    sC[r][128+c4+2] = has ? fdec(f2.z) : 0.f;
    sC[r][128+c4+3] = has ? fdec(f2.w) : 0.f;
  }
  __syncthreads();

  const int c0 = (t & 15) * 4, r0 = (t >> 4) * 4;
  float acc[4][4];

  {
    const float4 b4 = *(const float4*)&redb[c0];
    #pragma unroll
    for (int j = 0; j < 4; ++j){ acc[j][0]=b4.x; acc[j][1]=b4.y; acc[j][2]=b4.z; acc[j][3]=b4.w; }
    #pragma unroll 4
    for (int k = 0; k < 192; ++k){
      const float4 w4 = *(const float4*)&redw[k*64 + c0];
      #pragma unroll
      for (int j = 0; j < 4; ++j){
        const float a = sC[r0+j][k];
        acc[j][0] = fmaf(a, w4.x, acc[j][0]);
        acc[j][1] = fmaf(a, w4.y, acc[j][1]);
        acc[j][2] = fmaf(a, w4.z, acc[j][2]);
        acc[j][3] = fmaf(a, w4.w, acc[j][3]);
      }
    }
    #pragma unroll
    for (int j = 0; j < 4; ++j)
      #pragma unroll
      for (int i = 0; i < 4; ++i) sN[r0+j][c0+i] = acc[j][i];
  }
  __syncthreads();

  gemm64(sN, l2w, l2b, t, acc);
  #pragma unroll
  for (int j = 0; j < 4; ++j){
    int n = n0 + r0 + j;
    if (n < NN){
      float4 cur = *(const float4*)&out[(size_t)n*64 + c0];
      cur.x += acc[j][0]; cur.y += acc[j][1]; cur.z += acc[j][2]; cur.w += acc[j][3];
      *(float4*)&out[(size_t)n*64 + c0] = cur;
    }
  }
}

extern "C" void kernel_launch(void* const* d_in, const int* in_sizes, int n_in,
                              void* d_out, int out_size, void* d_ws, size_t ws_size,
                              hipStream_t stream)
{
  const float* nf   = (const float*)d_in[0];
  const int*   src  = (const int*)d_in[1];
  const int*   dst  = (const int*)d_in[2];
  const float* rw1  = (const float*)d_in[3];
  const float* rb1  = (const float*)d_in[4];
  const float* rw2  = (const float*)d_in[5];
  const float* rb2  = (const float*)d_in[6];
  const float* l1w  = (const float*)d_in[7];
  const float* l1b  = (const float*)d_in[8];
  const float* l2w  = (const float*)d_in[9];
  const float* l2b  = (const float*)d_in[10];
  const float* mw1  = (const float*)d_in[11];
  const float* mb1  = (const float*)d_in[12];
  const float* mw2  = (const float*)d_in[13];
  const float* mb2  = (const float*)d_in[14];
  const float* redw = (const float*)d_in[15];
  const float* redb = (const float*)d_in[16];

  float* ws = (float*)d_ws;
  float*     x      = ws + XOFF;
  _Float16*  P      = (_Float16*)(ws + POFF);
  _Float16*  Q      = (_Float16*)(ws + QOFF);
  float*     nfoc1  = ws + N1OFF;
  unsigned*  nfoc2  = (unsigned*)(ws + N2OFF);
  _Float16*  w2t    = (_Float16*)(ws + W2TOFF);
  float*     w2g    = ws + W2GOFF;
  unsigned*  counts = (unsigned*)(ws + CNTOFF);
  unsigned*  cursor = (unsigned*)(ws + CUROFF);
  unsigned*  partial= (unsigned*)(ws + PARTOFF);
  unsigned*  perm   = (unsigned*)(ws + PERMOFF);
  float*     out    = (float*)d_out;

  // zero: counts, and the contiguous nfoc1+nfoc2 region (0u == -inf sentinel for fenc)
  hipMemsetAsync(counts, 0, NN * sizeof(unsigned), stream);
  hipMemsetAsync(nfoc1, 0, (size_t)NN * 64 * 2 * sizeof(float), stream);
  hipLaunchKernelGGL(prep_k, dim3(65 + 3125), dim3(256), 0, stream, mw2, w2t, w2g, dst, counts);
  hipLaunchKernelGGL(scanA, dim3(196), dim3(256), 0, stream, counts, partial);
  hipLaunchKernelGGL(scanB, dim3(1),   dim3(256), 0, stream, partial, 196);
  hipLaunchKernelGGL(scanC, dim3(196), dim3(256), 0, stream, counts, partial, cursor);
  hipLaunchKernelGGL(assign_k, dim3(3125), dim3(256), 0, stream, dst, cursor, perm);
  hipLaunchKernelGGL(node_pre, dim3(782), dim3(256), 0, stream,
                     nf, rw1, rb1, rw2, rb2, l1w, l1b, mw1, x, P, Q, out);
  hipLaunchKernelGGL(edge_mlp5, dim3(12500), dim3(256), 0, stream,
                     src, dst, P, Q, mb1, w2t, w2g, mb2, perm, nfoc1, nfoc2);
  hipLaunchKernelGGL(node_post, dim3(782), dim3(256), 0, stream,
                     x, nfoc1, nfoc2, counts, redw, redb, l2w, l2b, out);
}

// Round 7
// 653.791 us; speedup vs baseline: 1.0034x; 1.0034x over previous
//
#include <hip/hip_runtime.h>

#define NN 50000
#define NE 800000

typedef _Float16 half8 __attribute__((ext_vector_type(8)));
typedef _Float16 half4 __attribute__((ext_vector_type(4)));
typedef float f32x4 __attribute__((ext_vector_type(4)));
typedef unsigned long long u64;

// ws layout (float offsets)
static const size_t XOFF   = 0;          // x      [50000*64] f32
static const size_t POFF   = 3200000;    // P      [50000*128] f16
static const size_t QOFF   = 6400000;    // Q      [50000*128] f16
static const size_t N1OFF  = 9600000;    // nfoc1  [50000*64] f32
static const size_t N2OFF  = 12800000;   // nfoc2  [50000*64] u32 (monotonic-encoded)
static const size_t W2TOFF = 16000000;   // w2t    [128 cols][128 k] f16 (col-major)
static const size_t W2GOFF = 16008192;   // w2gate [128] f32
static const size_t CNTOFF = 16008320;   // counts [50000] u32
static const size_t CUROFF = 16058320;   // cursor [50000] u32
static const size_t PARTOFF= 16108320;   // partial[256] u32
static const size_t SDOFF  = 16108576;   // sdbuf  [800000] u64 (16B-aligned: even float off)

__device__ __forceinline__ unsigned fenc(float f){
  unsigned b = __float_as_uint(f);
  return (b & 0x80000000u) ? ~b : (b | 0x80000000u);
}
__device__ __forceinline__ float fdec(unsigned u){
  return (u & 0x80000000u) ? __uint_as_float(u & 0x7fffffffu) : __uint_as_float(~u);
}
__device__ __forceinline__ float lrelu(float v){ return v > 0.f ? v : 0.2f * v; }

// 64x64 tile GEMM: acc[4][4] = bias + sIn(64x64, pad65) @ W(64x64 row-major)
__device__ __forceinline__ void gemm64(const float (*sIn)[65], const float* __restrict__ W,
                                       const float* __restrict__ bias, int t, float acc[4][4])
{
  const int c0 = (t & 15) * 4, r0 = (t >> 4) * 4;
  const float4 b4 = *(const float4*)&bias[c0];
  #pragma unroll
  for (int j = 0; j < 4; ++j){ acc[j][0]=b4.x; acc[j][1]=b4.y; acc[j][2]=b4.z; acc[j][3]=b4.w; }
  #pragma unroll 4
  for (int k = 0; k < 64; ++k){
    const float4 w4 = *(const float4*)&W[k*64 + c0];
    #pragma unroll
    for (int j = 0; j < 4; ++j){
      const float a = sIn[r0+j][k];
      acc[j][0] = fmaf(a, w4.x, acc[j][0]);
      acc[j][1] = fmaf(a, w4.y, acc[j][1]);
      acc[j][2] = fmaf(a, w4.z, acc[j][2]);
      acc[j][3] = fmaf(a, w4.w, acc[j][3]);
    }
  }
}

// blocks 0..64: msg_w2 [128][129] -> w2t f16 col-major + w2gate f32.
// blocks 65+: histogram of dst (counts pre-zeroed by memset).
__global__ __launch_bounds__(256) void prep_k(const float* __restrict__ w2,
                                              _Float16* __restrict__ w2t,
                                              float* __restrict__ w2g,
                                              const int* __restrict__ dst,
                                              unsigned* __restrict__ counts)
{
  const int b = blockIdx.x;
  if (b < 65){
    int i = b * 256 + threadIdx.x;
    if (i < 16384){
      int c = i >> 7, k = i & 127;
      w2t[i] = (_Float16)w2[k*129 + 1 + c];
    } else if (i < 16512){
      int k = i - 16384;
      w2g[k] = w2[k*129];
    }
  } else {
    int e = (b - 65) * 256 + threadIdx.x;
    if (e < NE) atomicAdd(&counts[dst[e]], 1u);
  }
}

// per-block sums of counts -> partial[196]
__global__ __launch_bounds__(256) void scanA(const unsigned* __restrict__ counts,
                                             unsigned* __restrict__ partial)
{
  __shared__ unsigned s[256];
  const int t = threadIdx.x;
  const int idx = blockIdx.x * 256 + t;
  s[t] = (idx < NN) ? counts[idx] : 0u;
  __syncthreads();
  for (int d = 128; d > 0; d >>= 1){
    if (t < d) s[t] += s[t + d];
    __syncthreads();
  }
  if (t == 0) partial[blockIdx.x] = s[0];
}

// exclusive scan of partial[196] in place (256 padded)
__global__ __launch_bounds__(256) void scanB(unsigned* __restrict__ partial, int nb)
{
  __shared__ unsigned s[256];
  const int t = threadIdx.x;
  unsigned v = (t < nb) ? partial[t] : 0u;
  s[t] = v;
  __syncthreads();
  for (int d = 1; d < 256; d <<= 1){
    unsigned u = (t >= d) ? s[t - d] : 0u;
    __syncthreads();
    s[t] += u;
    __syncthreads();
  }
  if (t < nb) partial[t] = s[t] - v;   // exclusive
}

// block-local exclusive scan + global offset -> cursor
__global__ __launch_bounds__(256) void scanC(const unsigned* __restrict__ counts,
                                             const unsigned* __restrict__ partial,
                                             unsigned* __restrict__ cursor)
{
  __shared__ unsigned s[256];
  const int t = threadIdx.x;
  const int idx = blockIdx.x * 256 + t;
  unsigned v = (idx < NN) ? counts[idx] : 0u;
  s[t] = v;
  __syncthreads();
  for (int d = 1; d < 256; d <<= 1){
    unsigned u = (t >= d) ? s[t - d] : 0u;
    __syncthreads();
    s[t] += u;
    __syncthreads();
  }
  if (idx < NN) cursor[idx] = partial[blockIdx.x] + s[t] - v;
}

// slot assignment: sdbuf[slot] = (dst<<32)|src, slots grouped by dst
__global__ __launch_bounds__(256) void assign_k(const int* __restrict__ src,
                                                const int* __restrict__ dst,
                                                unsigned* __restrict__ cursor,
                                                u64* __restrict__ sdbuf)
{
  int e = blockIdx.x * 256 + threadIdx.x;
  if (e < NE){
    const int d = dst[e];
    unsigned slot = atomicAdd(&cursor[d], 1u);
    sdbuf[slot] = ((u64)(unsigned)d << 32) | (unsigned)src[e];
  }
}

// Node-side precompute: x = residual(nf); x1 = x@l1w+b -> out; P/Q = x@W1 halves (f16).
__global__ __launch_bounds__(256) void node_pre(
    const float* __restrict__ nf,
    const float* __restrict__ rw1, const float* __restrict__ rb1,
    const float* __restrict__ rw2, const float* __restrict__ rb2,
    const float* __restrict__ l1w, const float* __restrict__ l1b,
    const float* __restrict__ w1,   // msg_w1 [128][128]
    float* __restrict__ x_out, _Float16* __restrict__ Pp, _Float16* __restrict__ Qp,
    float* __restrict__ out)
{
  __shared__ float sA[64][65];
  __shared__ float sB[64][65];
  const int t = threadIdx.x;
  const int n0 = blockIdx.x * 64;
  const int rr = t >> 4, c4 = (t & 15) * 4;

  #pragma unroll
  for (int i = 0; i < 4; ++i){
    int r = rr + i*16, n = n0 + r;
    float4 v = make_float4(0.f,0.f,0.f,0.f);
    if (n < NN) v = *(const float4*)&nf[n*64 + c4];
    sA[r][c4+0]=v.x; sA[r][c4+1]=v.y; sA[r][c4+2]=v.z; sA[r][c4+3]=v.w;
  }
  __syncthreads();

  float acc[4][4];
  const int c0 = (t & 15) * 4, r0 = (t >> 4) * 4;

  gemm64(sA, rw1, rb1, t, acc);
  #pragma unroll
  for (int j = 0; j < 4; ++j)
    #pragma unroll
    for (int i = 0; i < 4; ++i) sB[r0+j][c0+i] = acc[j][i];
  __syncthreads();

  gemm64(sB, rw2, rb2, t, acc);
  #pragma unroll
  for (int j = 0; j < 4; ++j)
    #pragma unroll
    for (int i = 0; i < 4; ++i) acc[j][i] += sA[r0+j][c0+i];
  __syncthreads();
  #pragma unroll
  for (int j = 0; j < 4; ++j){
    #pragma unroll
    for (int i = 0; i < 4; ++i) sA[r0+j][c0+i] = acc[j][i];
    int n = n0 + r0 + j;
    if (n < NN){
      float4 v = make_float4(acc[j][0],acc[j][1],acc[j][2],acc[j][3]);
      *(float4*)&x_out[n*64 + c0] = v;
    }
  }
  __syncthreads();

  gemm64(sA, l1w, l1b, t, acc);
  #pragma unroll
  for (int j = 0; j < 4; ++j){
    int n = n0 + r0 + j;
    if (n < NN){
      float4 v = make_float4(acc[j][0],acc[j][1],acc[j][2],acc[j][3]);
      *(float4*)&out[n*64 + c0] = v;
    }
  }

  #pragma unroll
  for (int part = 0; part < 2; ++part){
    _Float16* dstp = part ? Qp : Pp;
    const float* Wp = w1 + (size_t)part * 64 * 128;
    for (int ch = 0; ch < 2; ++ch){
      float a2[4][4];
      #pragma unroll
      for (int j = 0; j < 4; ++j)
        #pragma unroll
        for (int i = 0; i < 4; ++i) a2[j][i] = 0.f;
      #pragma unroll 4
      for (int k = 0; k < 64; ++k){
        const float4 w4 = *(const float4*)&Wp[k*128 + ch*64 + c0];
        #pragma unroll
        for (int j = 0; j < 4; ++j){
          const float a = sA[r0+j][k];
          a2[j][0] = fmaf(a, w4.x, a2[j][0]);
          a2[j][1] = fmaf(a, w4.y, a2[j][1]);
          a2[j][2] = fmaf(a, w4.z, a2[j][2]);
          a2[j][3] = fmaf(a, w4.w, a2[j][3]);
        }
      }
      #pragma unroll
      for (int j = 0; j < 4; ++j){
        int n = n0 + r0 + j;
        if (n < NN){
          half4 v;
          #pragma unroll
          for (int i = 0; i < 4; ++i) v[i] = (_Float16)a2[j][i];
          *(half4*)&dstp[(size_t)n*128 + ch*64 + c0] = v;
        }
      }
    }
  }
}

// Edge MLP: register-gathered MFMA (no LDS mid, one barrier) + block-segmented reduce.
// 64 dst-sorted edges per block; wave w owns rows 16w..16w+15.
__global__ __launch_bounds__(256) void edge_mlp6(
    const u64* __restrict__ sd,
    const _Float16* __restrict__ Pp, const _Float16* __restrict__ Qp,
    const float* __restrict__ b1,
    const _Float16* __restrict__ w2t, const float* __restrict__ w2g,
    const float* __restrict__ b2,
    float* __restrict__ nfoc1, unsigned* __restrict__ nfoc2)
{
  __shared__ _Float16 sOutH[64][136];  // gated o (f16)
  __shared__ int sD[64];
  const int t = threadIdx.x;
  const int lane = t & 63, wv = t >> 6;
  const int r  = lane & 15;     // edge row within wave tile (= A-row, B-col, D-col)
  const int kg = lane >> 4;     // k-group (= k-slice, D-row-quad)
  const int row0 = wv * 16;

  const u64 sdv = sd[blockIdx.x * 64 + row0 + r];
  const int s = (int)(unsigned)(sdv & 0xffffffffu);
  const int d = (int)(unsigned)(sdv >> 32);
  if (kg == 0) sD[row0 + r] = d;

  // gather A-fragments straight into MFMA layout + fused gate partial
  half4 af[8];
  float gp = 0.f;
  const _Float16* prow = &Pp[(size_t)s * 128];
  const _Float16* qrow = &Qp[(size_t)d * 128];
  #pragma unroll
  for (int kt = 0; kt < 8; ++kt){
    const int k0 = kt*16 + kg*4;
    const half4 ph = *(const half4*)&prow[k0];
    const half4 qh = *(const half4*)&qrow[k0];
    const float4 bb = *(const float4*)&b1[k0];
    const float4 wg = *(const float4*)&w2g[k0];
    float v0 = lrelu((float)ph[0] + (float)qh[0] + bb.x);
    float v1 = lrelu((float)ph[1] + (float)qh[1] + bb.y);
    float v2 = lrelu((float)ph[2] + (float)qh[2] + bb.z);
    float v3 = lrelu((float)ph[3] + (float)qh[3] + bb.w);
    gp = fmaf(v0, wg.x, fmaf(v1, wg.y, fmaf(v2, wg.z, fmaf(v3, wg.w, gp))));
    half4 m; m[0]=(_Float16)v0; m[1]=(_Float16)v1; m[2]=(_Float16)v2; m[3]=(_Float16)v3;
    af[kt] = m;
  }
  gp += __shfl_xor(gp, 16);
  gp += __shfl_xor(gp, 32);
  const float gate = 1.f / (1.f + expf(-(gp + b2[0])));
  float gr[4];
  #pragma unroll
  for (int j = 0; j < 4; ++j) gr[j] = __shfl(gate, kg*4 + j);

  // o = mid @ w2 via MFMA; gate+bias in regs; store f16 to LDS
  for (int ct = 0; ct < 8; ++ct){
    const int col = ct*16 + r;
    const _Float16* wc = &w2t[(size_t)col * 128 + kg*4];
    f32x4 acc = {0.f, 0.f, 0.f, 0.f};
    #pragma unroll
    for (int kt = 0; kt < 8; ++kt){
      const half4 bf = *(const half4*)&wc[kt*16];
      acc = __builtin_amdgcn_mfma_f32_16x16x16f16(af[kt], bf, acc, 0, 0, 0);
    }
    const float bc = b2[1 + col];
    #pragma unroll
    for (int reg = 0; reg < 4; ++reg)
      sOutH[row0 + kg*4 + reg][col] = (_Float16)((acc[reg] + bc) * gr[reg]);
  }
  __syncthreads();

  // block-segmented reduce over 64 dst-sorted rows; 2 threads/col x 32 rows each.
  {
    const int c = t & 127;
    const int rbeg = (t >> 7) * 32;
    const bool isSum = c < 64;
    float acc = isSum ? 0.f : -1e30f;
    int curd = sD[rbeg];
    for (int rr = rbeg; rr < rbeg + 32; ++rr){
      const float v = (float)sOutH[rr][c];
      acc = isSum ? (acc + v) : fmaxf(acc, v);
      const bool last = (rr == rbeg + 31) || (sD[rr + 1] != curd);
      if (last){
        if (isSum){
          unsafeAtomicAdd(&nfoc1[(size_t)curd*64 + c], acc);
          acc = 0.f;
        } else {
          atomicMax(&nfoc2[(size_t)curd*64 + (c - 64)], fenc(acc));
          acc = -1e30f;
        }
        if (rr < rbeg + 31) curd = sD[rr + 1];
      }
    }
  }
}

// Node-side post: new_x = concat(x,nfoc1,dec(nfoc2))@red_w+red_b; out += new_x@l2w+l2b
__global__ __launch_bounds__(256) void node_post(
    const float* __restrict__ x, const float* __restrict__ nfoc1,
    const unsigned* __restrict__ nfoc2, const unsigned* __restrict__ counts,
    const float* __restrict__ redw, const float* __restrict__ redb,
    const float* __restrict__ l2w, const float* __restrict__ l2b,
    float* __restrict__ out)
{
  __shared__ float sC[64][197];
  __shared__ float sN[64][65];
  const int t = threadIdx.x;
  const int n0 = blockIdx.x * 64;
  const int rr = t >> 4, c4 = (t & 15) * 4;

  #pragma unroll
  for (int i = 0; i < 4; ++i){
    int r = rr + i*16, n = n0 + r;
    float4 xv = make_float4(0,0,0,0), f1 = make_float4(0,0,0,0);
    uint4 f2 = make_uint4(0,0,0,0);
    bool has = false;
    if (n < NN){
      xv = *(const float4*)&x[(size_t)n*64 + c4];
      f1 = *(const float4*)&nfoc1[(size_t)n*64 + c4];
      f2 = *(const uint4*)&nfoc2[(size_t)n*64 + c4];
      has = counts[n] > 0u;
    }
    sC[r][c4+0]=xv.x; sC[r][c4+1]=xv.y; sC[r][c4+2]=xv.z; sC[r][c4+3]=xv.w;
    sC[r][64+c4+0]=f1.x; sC[r][64+c4+1]=f1.y; sC[r][64+c4+2]=f1.z; sC[r][64+c4+3]=f1.w;
    sC[r][128+c4+0] = has ? fdec(f2.x) : 0.f;
    sC[r][128+c4+1] = has ? fdec(f2.y) : 0.f;
    sC[r][128+c4+2] = has ? fdec(f2.z) : 0.f;
    sC[r][128+c4+3] = has ? fdec(f2.w) : 0.f;
  }
  __syncthreads();

  const int c0 = (t & 15) * 4, r0 = (t >> 4) * 4;
  float acc[4][4];

  {
    const float4 b4 = *(const float4*)&redb[c0];
    #pragma unroll
    for (int j = 0; j < 4; ++j){ acc[j][0]=b4.x; acc[j][1]=b4.y; acc[j][2]=b4.z; acc[j][3]=b4.w; }
    #pragma unroll 4
    for (int k = 0; k < 192; ++k){
      const float4 w4 = *(const float4*)&redw[k*64 + c0];
      #pragma unroll
      for (int j = 0; j < 4; ++j){
        const float a = sC[r0+j][k];
        acc[j][0] = fmaf(a, w4.x, acc[j][0]);
        acc[j][1] = fmaf(a, w4.y, acc[j][1]);
        acc[j][2] = fmaf(a, w4.z, acc[j][2]);
        acc[j][3] = fmaf(a, w4.w, acc[j][3]);
      }
    }
    #pragma unroll
    for (int j = 0; j < 4; ++j)
      #pragma unroll
      for (int i = 0; i < 4; ++i) sN[r0+j][c0+i] = acc[j][i];
  }
  __syncthreads();

  gemm64(sN, l2w, l2b, t, acc);
  #pragma unroll
  for (int j = 0; j < 4; ++j){
    int n = n0 + r0 + j;
    if (n < NN){
      float4 cur = *(const float4*)&out[(size_t)n*64 + c0];
      cur.x += acc[j][0]; cur.y += acc[j][1]; cur.z += acc[j][2]; cur.w += acc[j][3];
      *(float4*)&out[(size_t)n*64 + c0] = cur;
    }
  }
}

extern "C" void kernel_launch(void* const* d_in, const int* in_sizes, int n_in,
                              void* d_out, int out_size, void* d_ws, size_t ws_size,
                              hipStream_t stream)
{
  const float* nf   = (const float*)d_in[0];
  const int*   src  = (const int*)d_in[1];
  const int*   dst  = (const int*)d_in[2];
  const float* rw1  = (const float*)d_in[3];
  const float* rb1  = (const float*)d_in[4];
  const float* rw2  = (const float*)d_in[5];
  const float* rb2  = (const float*)d_in[6];
  const float* l1w  = (const float*)d_in[7];
  const float* l1b  = (const float*)d_in[8];
  const float* l2w  = (const float*)d_in[9];
  const float* l2b  = (const float*)d_in[10];
  const float* mw1  = (const float*)d_in[11];
  const float* mb1  = (const float*)d_in[12];
  const float* mw2  = (const float*)d_in[13];
  const float* mb2  = (const float*)d_in[14];
  const float* redw = (const float*)d_in[15];
  const float* redb = (const float*)d_in[16];

  float* ws = (float*)d_ws;
  float*     x      = ws + XOFF;
  _Float16*  P      = (_Float16*)(ws + POFF);
  _Float16*  Q      = (_Float16*)(ws + QOFF);
  float*     nfoc1  = ws + N1OFF;
  unsigned*  nfoc2  = (unsigned*)(ws + N2OFF);
  _Float16*  w2t    = (_Float16*)(ws + W2TOFF);
  float*     w2g    = ws + W2GOFF;
  unsigned*  counts = (unsigned*)(ws + CNTOFF);
  unsigned*  cursor = (unsigned*)(ws + CUROFF);
  unsigned*  partial= (unsigned*)(ws + PARTOFF);
  u64*       sdbuf  = (u64*)(ws + SDOFF);
  float*     out    = (float*)d_out;

  // zero: counts, and the contiguous nfoc1+nfoc2 region (0u == -inf sentinel for fenc)
  hipMemsetAsync(counts, 0, NN * sizeof(unsigned), stream);
  hipMemsetAsync(nfoc1, 0, (size_t)NN * 64 * 2 * sizeof(float), stream);
  hipLaunchKernelGGL(prep_k, dim3(65 + 3125), dim3(256), 0, stream, mw2, w2t, w2g, dst, counts);
  hipLaunchKernelGGL(scanA, dim3(196), dim3(256), 0, stream, counts, partial);
  hipLaunchKernelGGL(scanB, dim3(1),   dim3(256), 0, stream, partial, 196);
  hipLaunchKernelGGL(scanC, dim3(196), dim3(256), 0, stream, counts, partial, cursor);
  hipLaunchKernelGGL(assign_k, dim3(3125), dim3(256), 0, stream, src, dst, cursor, sdbuf);
  hipLaunchKernelGGL(node_pre, dim3(782), dim3(256), 0, stream,
                     nf, rw1, rb1, rw2, rb2, l1w, l1b, mw1, x, P, Q, out);
  hipLaunchKernelGGL(edge_mlp6, dim3(12500), dim3(256), 0, stream,
                     sdbuf, P, Q, mb1, w2t, w2g, mb2, nfoc1, nfoc2);
  hipLaunchKernelGGL(node_post, dim3(782), dim3(256), 0, stream,
                     x, nfoc1, nfoc2, counts, redw, redb, l2w, l2b, out);
}

// Round 8
// 416.914 us; speedup vs baseline: 1.5735x; 1.5682x over previous
//
#include <hip/hip_runtime.h>

#define NN 50000
#define NE 800000

typedef _Float16 half8 __attribute__((ext_vector_type(8)));
typedef _Float16 half4 __attribute__((ext_vector_type(4)));
typedef float f32x4 __attribute__((ext_vector_type(4)));
typedef unsigned long long u64;

// ws layout (float offsets)
static const size_t XOFF   = 0;          // x      [50000*64] f32
static const size_t POFF   = 3200000;    // P      [50000*128] f16
static const size_t QOFF   = 6400000;    // Q      [50000*128] f16
static const size_t N1OFF  = 9600000;    // nfoc1  [50000*64] f32
static const size_t N2OFF  = 12800000;   // nfoc2  [50000*64] u32 (monotonic-encoded)
static const size_t W2TOFF = 16000000;   // w2t    [128 cols][128 k] f16 (col-major)
static const size_t W2GOFF = 16008192;   // w2gate [128] f32
static const size_t CNTOFF = 16008320;   // counts [50000] u32
static const size_t CUROFF = 16058320;   // cursor [50000] u32
static const size_t PARTOFF= 16108320;   // partial[256] u32
static const size_t SDOFF  = 16108576;   // sdbuf  [800000] u64 (16B-aligned: even float off)

__device__ __forceinline__ unsigned fenc(float f){
  unsigned b = __float_as_uint(f);
  return (b & 0x80000000u) ? ~b : (b | 0x80000000u);
}
__device__ __forceinline__ float fdec(unsigned u){
  return (u & 0x80000000u) ? __uint_as_float(u & 0x7fffffffu) : __uint_as_float(~u);
}
__device__ __forceinline__ float lrelu(float v){ return v > 0.f ? v : 0.2f * v; }

// 64x64 tile GEMM: acc[4][4] = bias + sIn(64x64, pad65) @ W(64x64 row-major)
__device__ __forceinline__ void gemm64(const float (*sIn)[65], const float* __restrict__ W,
                                       const float* __restrict__ bias, int t, float acc[4][4])
{
  const int c0 = (t & 15) * 4, r0 = (t >> 4) * 4;
  const float4 b4 = *(const float4*)&bias[c0];
  #pragma unroll
  for (int j = 0; j < 4; ++j){ acc[j][0]=b4.x; acc[j][1]=b4.y; acc[j][2]=b4.z; acc[j][3]=b4.w; }
  #pragma unroll 4
  for (int k = 0; k < 64; ++k){
    const float4 w4 = *(const float4*)&W[k*64 + c0];
    #pragma unroll
    for (int j = 0; j < 4; ++j){
      const float a = sIn[r0+j][k];
      acc[j][0] = fmaf(a, w4.x, acc[j][0]);
      acc[j][1] = fmaf(a, w4.y, acc[j][1]);
      acc[j][2] = fmaf(a, w4.z, acc[j][2]);
      acc[j][3] = fmaf(a, w4.w, acc[j][3]);
    }
  }
}

// blocks 0..64: msg_w2 [128][129] -> w2t f16 col-major + w2gate f32.
// blocks 65+: histogram of dst (counts pre-zeroed by memset).
__global__ __launch_bounds__(256) void prep_k(const float* __restrict__ w2,
                                              _Float16* __restrict__ w2t,
                                              float* __restrict__ w2g,
                                              const int* __restrict__ dst,
                                              unsigned* __restrict__ counts)
{
  const int b = blockIdx.x;
  if (b < 65){
    int i = b * 256 + threadIdx.x;
    if (i < 16384){
      int c = i >> 7, k = i & 127;
      w2t[i] = (_Float16)w2[k*129 + 1 + c];
    } else if (i < 16512){
      int k = i - 16384;
      w2g[k] = w2[k*129];
    }
  } else {
    int e = (b - 65) * 256 + threadIdx.x;
    if (e < NE) atomicAdd(&counts[dst[e]], 1u);
  }
}

// per-block sums of counts -> partial[196]
__global__ __launch_bounds__(256) void scanA(const unsigned* __restrict__ counts,
                                             unsigned* __restrict__ partial)
{
  __shared__ unsigned s[256];
  const int t = threadIdx.x;
  const int idx = blockIdx.x * 256 + t;
  s[t] = (idx < NN) ? counts[idx] : 0u;
  __syncthreads();
  for (int d = 128; d > 0; d >>= 1){
    if (t < d) s[t] += s[t + d];
    __syncthreads();
  }
  if (t == 0) partial[blockIdx.x] = s[0];
}

// exclusive scan of partial[196] in place (256 padded)
__global__ __launch_bounds__(256) void scanB(unsigned* __restrict__ partial, int nb)
{
  __shared__ unsigned s[256];
  const int t = threadIdx.x;
  unsigned v = (t < nb) ? partial[t] : 0u;
  s[t] = v;
  __syncthreads();
  for (int d = 1; d < 256; d <<= 1){
    unsigned u = (t >= d) ? s[t - d] : 0u;
    __syncthreads();
    s[t] += u;
    __syncthreads();
  }
  if (t < nb) partial[t] = s[t] - v;   // exclusive
}

// block-local exclusive scan + global offset -> cursor
__global__ __launch_bounds__(256) void scanC(const unsigned* __restrict__ counts,
                                             const unsigned* __restrict__ partial,
                                             unsigned* __restrict__ cursor)
{
  __shared__ unsigned s[256];
  const int t = threadIdx.x;
  const int idx = blockIdx.x * 256 + t;
  unsigned v = (idx < NN) ? counts[idx] : 0u;
  s[t] = v;
  __syncthreads();
  for (int d = 1; d < 256; d <<= 1){
    unsigned u = (t >= d) ? s[t - d] : 0u;
    __syncthreads();
    s[t] += u;
    __syncthreads();
  }
  if (idx < NN) cursor[idx] = partial[blockIdx.x] + s[t] - v;
}

// slot assignment: sdbuf[slot] = (dst<<32)|src, slots grouped by dst
__global__ __launch_bounds__(256) void assign_k(const int* __restrict__ src,
                                                const int* __restrict__ dst,
                                                unsigned* __restrict__ cursor,
                                                u64* __restrict__ sdbuf)
{
  int e = blockIdx.x * 256 + threadIdx.x;
  if (e < NE){
    const int d = dst[e];
    unsigned slot = atomicAdd(&cursor[d], 1u);
    sdbuf[slot] = ((u64)(unsigned)d << 32) | (unsigned)src[e];
  }
}

// Node-side precompute: x = residual(nf); x1 = x@l1w+b -> out; P/Q = x@W1 halves (f16).
__global__ __launch_bounds__(256) void node_pre(
    const float* __restrict__ nf,
    const float* __restrict__ rw1, const float* __restrict__ rb1,
    const float* __restrict__ rw2, const float* __restrict__ rb2,
    const float* __restrict__ l1w, const float* __restrict__ l1b,
    const float* __restrict__ w1,   // msg_w1 [128][128]
    float* __restrict__ x_out, _Float16* __restrict__ Pp, _Float16* __restrict__ Qp,
    float* __restrict__ out)
{
  __shared__ float sA[64][65];
  __shared__ float sB[64][65];
  const int t = threadIdx.x;
  const int n0 = blockIdx.x * 64;
  const int rr = t >> 4, c4 = (t & 15) * 4;

  #pragma unroll
  for (int i = 0; i < 4; ++i){
    int r = rr + i*16, n = n0 + r;
    float4 v = make_float4(0.f,0.f,0.f,0.f);
    if (n < NN) v = *(const float4*)&nf[n*64 + c4];
    sA[r][c4+0]=v.x; sA[r][c4+1]=v.y; sA[r][c4+2]=v.z; sA[r][c4+3]=v.w;
  }
  __syncthreads();

  float acc[4][4];
  const int c0 = (t & 15) * 4, r0 = (t >> 4) * 4;

  gemm64(sA, rw1, rb1, t, acc);
  #pragma unroll
  for (int j = 0; j < 4; ++j)
    #pragma unroll
    for (int i = 0; i < 4; ++i) sB[r0+j][c0+i] = acc[j][i];
  __syncthreads();

  gemm64(sB, rw2, rb2, t, acc);
  #pragma unroll
  for (int j = 0; j < 4; ++j)
    #pragma unroll
    for (int i = 0; i < 4; ++i) acc[j][i] += sA[r0+j][c0+i];
  __syncthreads();
  #pragma unroll
  for (int j = 0; j < 4; ++j){
    #pragma unroll
    for (int i = 0; i < 4; ++i) sA[r0+j][c0+i] = acc[j][i];
    int n = n0 + r0 + j;
    if (n < NN){
      float4 v = make_float4(acc[j][0],acc[j][1],acc[j][2],acc[j][3]);
      *(float4*)&x_out[n*64 + c0] = v;
    }
  }
  __syncthreads();

  gemm64(sA, l1w, l1b, t, acc);
  #pragma unroll
  for (int j = 0; j < 4; ++j){
    int n = n0 + r0 + j;
    if (n < NN){
      float4 v = make_float4(acc[j][0],acc[j][1],acc[j][2],acc[j][3]);
      *(float4*)&out[n*64 + c0] = v;
    }
  }

  #pragma unroll
  for (int part = 0; part < 2; ++part){
    _Float16* dstp = part ? Qp : Pp;
    const float* Wp = w1 + (size_t)part * 64 * 128;
    for (int ch = 0; ch < 2; ++ch){
      float a2[4][4];
      #pragma unroll
      for (int j = 0; j < 4; ++j)
        #pragma unroll
        for (int i = 0; i < 4; ++i) a2[j][i] = 0.f;
      #pragma unroll 4
      for (int k = 0; k < 64; ++k){
        const float4 w4 = *(const float4*)&Wp[k*128 + ch*64 + c0];
        #pragma unroll
        for (int j = 0; j < 4; ++j){
          const float a = sA[r0+j][k];
          a2[j][0] = fmaf(a, w4.x, a2[j][0]);
          a2[j][1] = fmaf(a, w4.y, a2[j][1]);
          a2[j][2] = fmaf(a, w4.z, a2[j][2]);
          a2[j][3] = fmaf(a, w4.w, a2[j][3]);
        }
      }
      #pragma unroll
      for (int j = 0; j < 4; ++j){
        int n = n0 + r0 + j;
        if (n < NN){
          half4 v;
          #pragma unroll
          for (int i = 0; i < 4; ++i) v[i] = (_Float16)a2[j][i];
          *(half4*)&dstp[(size_t)n*128 + ch*64 + c0] = v;
        }
      }
    }
  }
}

// Edge MLP v7: register A-gather -> LDS fragment tile; B hoisted to 32 VGPRs;
// inner loop = ds_read + MFMA only. 64 dst-sorted edges/block, 2 barriers.
__global__ __launch_bounds__(256) void edge_mlp7(
    const u64* __restrict__ sd,
    const _Float16* __restrict__ Pp, const _Float16* __restrict__ Qp,
    const float* __restrict__ b1,
    const _Float16* __restrict__ w2t, const float* __restrict__ w2g,
    const float* __restrict__ b2,
    float* __restrict__ nfoc1, unsigned* __restrict__ nfoc2)
{
  __shared__ _Float16 sA[64][136];     // mid in fragment-friendly layout (pad: 2-way max)
  __shared__ _Float16 sOutH[64][136];  // raw o+bias (f16)
  __shared__ float sK[64];
  __shared__ int   sD[64];
  const int t = threadIdx.x;
  const int lane = t & 63, wv = t >> 6;
  const int r  = lane & 15;     // A-row / B-col / D-col index
  const int kg = lane >> 4;     // k-group / D-row-quad
  const int row0 = wv * 16;

  // hoist B-fragments for this wave's 2 col-tiles (independent global loads, L2-hot)
  const int ct0 = wv * 2;
  half4 bf[2][8];
  float bias_c[2];
  #pragma unroll
  for (int cc = 0; cc < 2; ++cc){
    const int col = (ct0 + cc)*16 + r;
    bias_c[cc] = b2[1 + col];
    const _Float16* wc = &w2t[(size_t)col*128 + kg*4];
    #pragma unroll
    for (int kt = 0; kt < 8; ++kt)
      bf[cc][kt] = *(const half4*)&wc[kt*16];
  }

  // gather A-fragments for own 16 rows; write to sA; fused gate partial
  const u64 sdv = sd[blockIdx.x * 64 + row0 + r];
  const int s = (int)(unsigned)(sdv & 0xffffffffu);
  const int d = (int)(unsigned)(sdv >> 32);
  if (kg == 0) sD[row0 + r] = d;

  {
    float gp = 0.f;
    const _Float16* prow = &Pp[(size_t)s * 128];
    const _Float16* qrow = &Qp[(size_t)d * 128];
    #pragma unroll
    for (int kt = 0; kt < 8; ++kt){
      const int k0 = kt*16 + kg*4;
      const half4 ph = *(const half4*)&prow[k0];
      const half4 qh = *(const half4*)&qrow[k0];
      const float4 bb = *(const float4*)&b1[k0];
      const float4 wg = *(const float4*)&w2g[k0];
      float v0 = lrelu((float)ph[0] + (float)qh[0] + bb.x);
      float v1 = lrelu((float)ph[1] + (float)qh[1] + bb.y);
      float v2 = lrelu((float)ph[2] + (float)qh[2] + bb.z);
      float v3 = lrelu((float)ph[3] + (float)qh[3] + bb.w);
      gp = fmaf(v0, wg.x, fmaf(v1, wg.y, fmaf(v2, wg.z, fmaf(v3, wg.w, gp))));
      half4 m; m[0]=(_Float16)v0; m[1]=(_Float16)v1; m[2]=(_Float16)v2; m[3]=(_Float16)v3;
      *(half4*)&sA[row0 + r][k0] = m;
    }
    gp += __shfl_xor(gp, 16);
    gp += __shfl_xor(gp, 32);
    const float gate = 1.f / (1.f + expf(-(gp + b2[0])));
    if (kg == 0) sK[row0 + r] = gate;
  }
  __syncthreads();

  // MFMA: this wave computes cols [ct0*16, ct0*16+32) for all 64 rows.
  #pragma unroll
  for (int rt = 0; rt < 4; ++rt){
    half4 af[8];
    const _Float16* ar = &sA[rt*16 + r][kg*4];
    #pragma unroll
    for (int kt = 0; kt < 8; ++kt) af[kt] = *(const half4*)&ar[kt*16];
    f32x4 a0 = {0.f,0.f,0.f,0.f}, a1 = {0.f,0.f,0.f,0.f};
    #pragma unroll
    for (int kt = 0; kt < 8; ++kt){
      a0 = __builtin_amdgcn_mfma_f32_16x16x16f16(af[kt], bf[0][kt], a0, 0, 0, 0);
      a1 = __builtin_amdgcn_mfma_f32_16x16x16f16(af[kt], bf[1][kt], a1, 0, 0, 0);
    }
    #pragma unroll
    for (int reg = 0; reg < 4; ++reg){
      const int row = rt*16 + kg*4 + reg;
      sOutH[row][ ct0   *16 + r] = (_Float16)(a0[reg] + bias_c[0]);
      sOutH[row][(ct0+1)*16 + r] = (_Float16)(a1[reg] + bias_c[1]);
    }
  }
  __syncthreads();

  // block-segmented reduce over 64 dst-sorted rows (gate applied here)
  {
    const int c = t & 127;
    const int rbeg = (t >> 7) * 32;
    const bool isSum = c < 64;
    float acc = isSum ? 0.f : -1e30f;
    int curd = sD[rbeg];
    for (int rr = rbeg; rr < rbeg + 32; ++rr){
      const float v = (float)sOutH[rr][c] * sK[rr];
      acc = isSum ? (acc + v) : fmaxf(acc, v);
      const bool last = (rr == rbeg + 31) || (sD[rr + 1] != curd);
      if (last){
        if (isSum){
          unsafeAtomicAdd(&nfoc1[(size_t)curd*64 + c], acc);
          acc = 0.f;
        } else {
          atomicMax(&nfoc2[(size_t)curd*64 + (c - 64)], fenc(acc));
          acc = -1e30f;
        }
        if (rr < rbeg + 31) curd = sD[rr + 1];
      }
    }
  }
}

// Node-side post: new_x = concat(x,nfoc1,dec(nfoc2))@red_w+red_b; out += new_x@l2w+l2b
__global__ __launch_bounds__(256) void node_post(
    const float* __restrict__ x, const float* __restrict__ nfoc1,
    const unsigned* __restrict__ nfoc2, const unsigned* __restrict__ counts,
    const float* __restrict__ redw, const float* __restrict__ redb,
    const float* __restrict__ l2w, const float* __restrict__ l2b,
    float* __restrict__ out)
{
  __shared__ float sC[64][197];
  __shared__ float sN[64][65];
  const int t = threadIdx.x;
  const int n0 = blockIdx.x * 64;
  const int rr = t >> 4, c4 = (t & 15) * 4;

  #pragma unroll
  for (int i = 0; i < 4; ++i){
    int r = rr + i*16, n = n0 + r;
    float4 xv = make_float4(0,0,0,0), f1 = make_float4(0,0,0,0);
    uint4 f2 = make_uint4(0,0,0,0);
    bool has = false;
    if (n < NN){
      xv = *(const float4*)&x[(size_t)n*64 + c4];
      f1 = *(const float4*)&nfoc1[(size_t)n*64 + c4];
      f2 = *(const uint4*)&nfoc2[(size_t)n*64 + c4];
      has = counts[n] > 0u;
    }
    sC[r][c4+0]=xv.x; sC[r][c4+1]=xv.y; sC[r][c4+2]=xv.z; sC[r][c4+3]=xv.w;
    sC[r][64+c4+0]=f1.x; sC[r][64+c4+1]=f1.y; sC[r][64+c4+2]=f1.z; sC[r][64+c4+3]=f1.w;
    sC[r][128+c4+0] = has ? fdec(f2.x) : 0.f;
    sC[r][128+c4+1] = has ? fdec(f2.y) : 0.f;
    sC[r][128+c4+2] = has ? fdec(f2.z) : 0.f;
    sC[r][128+c4+3] = has ? fdec(f2.w) : 0.f;
  }
  __syncthreads();

  const int c0 = (t & 15) * 4, r0 = (t >> 4) * 4;
  float acc[4][4];

  {
    const float4 b4 = *(const float4*)&redb[c0];
    #pragma unroll
    for (int j = 0; j < 4; ++j){ acc[j][0]=b4.x; acc[j][1]=b4.y; acc[j][2]=b4.z; acc[j][3]=b4.w; }
    #pragma unroll 4
    for (int k = 0; k < 192; ++k){
      const float4 w4 = *(const float4*)&redw[k*64 + c0];
      #pragma unroll
      for (int j = 0; j < 4; ++j){
        const float a = sC[r0+j][k];
        acc[j][0] = fmaf(a, w4.x, acc[j][0]);
        acc[j][1] = fmaf(a, w4.y, acc[j][1]);
        acc[j][2] = fmaf(a, w4.z, acc[j][2]);
        acc[j][3] = fmaf(a, w4.w, acc[j][3]);
      }
    }
    #pragma unroll
    for (int j = 0; j < 4; ++j)
      #pragma unroll
      for (int i = 0; i < 4; ++i) sN[r0+j][c0+i] = acc[j][i];
  }
  __syncthreads();

  gemm64(sN, l2w, l2b, t, acc);
  #pragma unroll
  for (int j = 0; j < 4; ++j){
    int n = n0 + r0 + j;
    if (n < NN){
      float4 cur = *(const float4*)&out[(size_t)n*64 + c0];
      cur.x += acc[j][0]; cur.y += acc[j][1]; cur.z += acc[j][2]; cur.w += acc[j][3];
      *(float4*)&out[(size_t)n*64 + c0] = cur;
    }
  }
}

extern "C" void kernel_launch(void* const* d_in, const int* in_sizes, int n_in,
                              void* d_out, int out_size, void* d_ws, size_t ws_size,
                              hipStream_t stream)
{
  const float* nf   = (const float*)d_in[0];
  const int*   src  = (const int*)d_in[1];
  const int*   dst  = (const int*)d_in[2];
  const float* rw1  = (const float*)d_in[3];
  const float* rb1  = (const float*)d_in[4];
  const float* rw2  = (const float*)d_in[5];
  const float* rb2  = (const float*)d_in[6];
  const float* l1w  = (const float*)d_in[7];
  const float* l1b  = (const float*)d_in[8];
  const float* l2w  = (const float*)d_in[9];
  const float* l2b  = (const float*)d_in[10];
  const float* mw1  = (const float*)d_in[11];
  const float* mb1  = (const float*)d_in[12];
  const float* mw2  = (const float*)d_in[13];
  const float* mb2  = (const float*)d_in[14];
  const float* redw = (const float*)d_in[15];
  const float* redb = (const float*)d_in[16];

  float* ws = (float*)d_ws;
  float*     x      = ws + XOFF;
  _Float16*  P      = (_Float16*)(ws + POFF);
  _Float16*  Q      = (_Float16*)(ws + QOFF);
  float*     nfoc1  = ws + N1OFF;
  unsigned*  nfoc2  = (unsigned*)(ws + N2OFF);
  _Float16*  w2t    = (_Float16*)(ws + W2TOFF);
  float*     w2g    = ws + W2GOFF;
  unsigned*  counts = (unsigned*)(ws + CNTOFF);
  unsigned*  cursor = (unsigned*)(ws + CUROFF);
  unsigned*  partial= (unsigned*)(ws + PARTOFF);
  u64*       sdbuf  = (u64*)(ws + SDOFF);
  float*     out    = (float*)d_out;

  // zero: counts, and the contiguous nfoc1+nfoc2 region (0u == -inf sentinel for fenc)
  hipMemsetAsync(counts, 0, NN * sizeof(unsigned), stream);
  hipMemsetAsync(nfoc1, 0, (size_t)NN * 64 * 2 * sizeof(float), stream);
  hipLaunchKernelGGL(prep_k, dim3(65 + 3125), dim3(256), 0, stream, mw2, w2t, w2g, dst, counts);
  hipLaunchKernelGGL(scanA, dim3(196), dim3(256), 0, stream, counts, partial);
  hipLaunchKernelGGL(scanB, dim3(1),   dim3(256), 0, stream, partial, 196);
  hipLaunchKernelGGL(scanC, dim3(196), dim3(256), 0, stream, counts, partial, cursor);
  hipLaunchKernelGGL(assign_k, dim3(3125), dim3(256), 0, stream, src, dst, cursor, sdbuf);
  hipLaunchKernelGGL(node_pre, dim3(782), dim3(256), 0, stream,
                     nf, rw1, rb1, rw2, rb2, l1w, l1b, mw1, x, P, Q, out);
  hipLaunchKernelGGL(edge_mlp7, dim3(12500), dim3(256), 0, stream,
                     sdbuf, P, Q, mb1, w2t, w2g, mb2, nfoc1, nfoc2);
  hipLaunchKernelGGL(node_post, dim3(782), dim3(256), 0, stream,
                     x, nfoc1, nfoc2, counts, redw, redb, l2w, l2b, out);
}

// Round 9
// 386.632 us; speedup vs baseline: 1.6967x; 1.0783x over previous
//
#include <hip/hip_runtime.h>

#define NN 50000
#define NE 800000

typedef _Float16 half8 __attribute__((ext_vector_type(8)));
typedef _Float16 half4 __attribute__((ext_vector_type(4)));
typedef float f32x4 __attribute__((ext_vector_type(4)));
typedef unsigned long long u64;

// ws layout (float offsets)
static const size_t XOFF   = 0;          // x      [50000*64] f32
static const size_t POFF   = 3200000;    // P      [50000*128] f16 (k-permuted)
static const size_t QOFF   = 6400000;    // Q      [50000*128] f16 (k-permuted)
static const size_t N1OFF  = 9600000;    // nfoc1  [50000*64] f32
static const size_t N2OFF  = 12800000;   // nfoc2  [50000*64] u32 (monotonic-encoded)
static const size_t W2TOFF = 16000000;   // w2t    [128 cols][128 k'] f16 (col-major, k-permuted)
static const size_t B1HOFF = 16008192;   // b1h    [128] f16 (k-permuted)
static const size_t WGHOFF = 16008256;   // w2gh   [128] f16 (k-permuted)
static const size_t CNTOFF = 16008320;   // counts [50000] u32
static const size_t CUROFF = 16058320;   // cursor [50000] u32
static const size_t PARTOFF= 16108320;   // partial[256] u32
static const size_t SDOFF  = 16108576;   // sdbuf  [800000] u64 (16B-aligned)

__device__ __forceinline__ unsigned fenc(float f){
  unsigned b = __float_as_uint(f);
  return (b & 0x80000000u) ? ~b : (b | 0x80000000u);
}
__device__ __forceinline__ float fdec(unsigned u){
  return (u & 0x80000000u) ? __uint_as_float(u & 0x7fffffffu) : __uint_as_float(~u);
}
__device__ __forceinline__ float lrelu(float v){ return v > 0.f ? v : 0.2f * v; }

// 64x64 tile GEMM: acc[4][4] = bias + sIn(64x64, pad65) @ W(64x64 row-major)
__device__ __forceinline__ void gemm64(const float (*sIn)[65], const float* __restrict__ W,
                                       const float* __restrict__ bias, int t, float acc[4][4])
{
  const int c0 = (t & 15) * 4, r0 = (t >> 4) * 4;
  const float4 b4 = *(const float4*)&bias[c0];
  #pragma unroll
  for (int j = 0; j < 4; ++j){ acc[j][0]=b4.x; acc[j][1]=b4.y; acc[j][2]=b4.z; acc[j][3]=b4.w; }
  #pragma unroll 4
  for (int k = 0; k < 64; ++k){
    const float4 w4 = *(const float4*)&W[k*64 + c0];
    #pragma unroll
    for (int j = 0; j < 4; ++j){
      const float a = sIn[r0+j][k];
      acc[j][0] = fmaf(a, w4.x, acc[j][0]);
      acc[j][1] = fmaf(a, w4.y, acc[j][1]);
      acc[j][2] = fmaf(a, w4.z, acc[j][2]);
      acc[j][3] = fmaf(a, w4.w, acc[j][3]);
    }
  }
}

// k-permutation: k' = kg*32 + kt*4 + j  <->  k = kt*16 + kg*4 + j
__device__ __forceinline__ int kperm(int kp){
  const int kg = kp >> 5, rem = kp & 31, kt = rem >> 2, j = rem & 3;
  return kt*16 + kg*4 + j;
}

// blocks 0..64: msg_w2 -> w2t (f16 col-major, k-permuted) + b1h + w2gh.
// blocks 65+: histogram of dst (counts pre-zeroed by memset).
__global__ __launch_bounds__(256) void prep_k(const float* __restrict__ w2,
                                              const float* __restrict__ mb1,
                                              _Float16* __restrict__ w2t,
                                              _Float16* __restrict__ b1h,
                                              _Float16* __restrict__ w2gh,
                                              const int* __restrict__ dst,
                                              unsigned* __restrict__ counts)
{
  const int b = blockIdx.x;
  if (b < 65){
    int i = b * 256 + threadIdx.x;
    if (i < 16384){
      int c = i >> 7, kp = i & 127;
      w2t[i] = (_Float16)w2[kperm(kp)*129 + 1 + c];
    } else if (i < 16512){
      int kp = i - 16384;
      int k = kperm(kp);
      w2gh[kp] = (_Float16)w2[k*129];
      b1h[kp]  = (_Float16)mb1[k];
    }
  } else {
    int e = (b - 65) * 256 + threadIdx.x;
    if (e < NE) atomicAdd(&counts[dst[e]], 1u);
  }
}

// per-block sums of counts -> partial[196]
__global__ __launch_bounds__(256) void scanA(const unsigned* __restrict__ counts,
                                             unsigned* __restrict__ partial)
{
  __shared__ unsigned s[256];
  const int t = threadIdx.x;
  const int idx = blockIdx.x * 256 + t;
  s[t] = (idx < NN) ? counts[idx] : 0u;
  __syncthreads();
  for (int d = 128; d > 0; d >>= 1){
    if (t < d) s[t] += s[t + d];
    __syncthreads();
  }
  if (t == 0) partial[blockIdx.x] = s[0];
}

// exclusive scan of partial[196] in place (256 padded)
__global__ __launch_bounds__(256) void scanB(unsigned* __restrict__ partial, int nb)
{
  __shared__ unsigned s[256];
  const int t = threadIdx.x;
  unsigned v = (t < nb) ? partial[t] : 0u;
  s[t] = v;
  __syncthreads();
  for (int d = 1; d < 256; d <<= 1){
    unsigned u = (t >= d) ? s[t - d] : 0u;
    __syncthreads();
    s[t] += u;
    __syncthreads();
  }
  if (t < nb) partial[t] = s[t] - v;   // exclusive
}

// block-local exclusive scan + global offset -> cursor
__global__ __launch_bounds__(256) void scanC(const unsigned* __restrict__ counts,
                                             const unsigned* __restrict__ partial,
                                             unsigned* __restrict__ cursor)
{
  __shared__ unsigned s[256];
  const int t = threadIdx.x;
  const int idx = blockIdx.x * 256 + t;
  unsigned v = (idx < NN) ? counts[idx] : 0u;
  s[t] = v;
  __syncthreads();
  for (int d = 1; d < 256; d <<= 1){
    unsigned u = (t >= d) ? s[t - d] : 0u;
    __syncthreads();
    s[t] += u;
    __syncthreads();
  }
  if (idx < NN) cursor[idx] = partial[blockIdx.x] + s[t] - v;
}

// slot assignment: sdbuf[slot] = (dst<<32)|src, slots grouped by dst
__global__ __launch_bounds__(256) void assign_k(const int* __restrict__ src,
                                                const int* __restrict__ dst,
                                                unsigned* __restrict__ cursor,
                                                u64* __restrict__ sdbuf)
{
  int e = blockIdx.x * 256 + threadIdx.x;
  if (e < NE){
    const int d = dst[e];
    unsigned slot = atomicAdd(&cursor[d], 1u);
    sdbuf[slot] = ((u64)(unsigned)d << 32) | (unsigned)src[e];
  }
}

// Node-side precompute: x = residual(nf); x1 = x@l1w+b -> out; P/Q = x@W1 halves
// (f16, k-permuted column layout).
__global__ __launch_bounds__(256) void node_pre(
    const float* __restrict__ nf,
    const float* __restrict__ rw1, const float* __restrict__ rb1,
    const float* __restrict__ rw2, const float* __restrict__ rb2,
    const float* __restrict__ l1w, const float* __restrict__ l1b,
    const float* __restrict__ w1,   // msg_w1 [128][128]
    float* __restrict__ x_out, _Float16* __restrict__ Pp, _Float16* __restrict__ Qp,
    float* __restrict__ out)
{
  __shared__ float sA[64][65];
  __shared__ float sB[64][65];
  const int t = threadIdx.x;
  const int n0 = blockIdx.x * 64;
  const int rr = t >> 4, c4 = (t & 15) * 4;

  #pragma unroll
  for (int i = 0; i < 4; ++i){
    int r = rr + i*16, n = n0 + r;
    float4 v = make_float4(0.f,0.f,0.f,0.f);
    if (n < NN) v = *(const float4*)&nf[n*64 + c4];
    sA[r][c4+0]=v.x; sA[r][c4+1]=v.y; sA[r][c4+2]=v.z; sA[r][c4+3]=v.w;
  }
  __syncthreads();

  float acc[4][4];
  const int c0 = (t & 15) * 4, r0 = (t >> 4) * 4;

  gemm64(sA, rw1, rb1, t, acc);
  #pragma unroll
  for (int j = 0; j < 4; ++j)
    #pragma unroll
    for (int i = 0; i < 4; ++i) sB[r0+j][c0+i] = acc[j][i];
  __syncthreads();

  gemm64(sB, rw2, rb2, t, acc);
  #pragma unroll
  for (int j = 0; j < 4; ++j)
    #pragma unroll
    for (int i = 0; i < 4; ++i) acc[j][i] += sA[r0+j][c0+i];
  __syncthreads();
  #pragma unroll
  for (int j = 0; j < 4; ++j){
    #pragma unroll
    for (int i = 0; i < 4; ++i) sA[r0+j][c0+i] = acc[j][i];
    int n = n0 + r0 + j;
    if (n < NN){
      float4 v = make_float4(acc[j][0],acc[j][1],acc[j][2],acc[j][3]);
      *(float4*)&x_out[n*64 + c0] = v;
    }
  }
  __syncthreads();

  gemm64(sA, l1w, l1b, t, acc);
  #pragma unroll
  for (int j = 0; j < 4; ++j){
    int n = n0 + r0 + j;
    if (n < NN){
      float4 v = make_float4(acc[j][0],acc[j][1],acc[j][2],acc[j][3]);
      *(float4*)&out[n*64 + c0] = v;
    }
  }

  #pragma unroll
  for (int part = 0; part < 2; ++part){
    _Float16* dstp = part ? Qp : Pp;
    const float* Wp = w1 + (size_t)part * 64 * 128;
    for (int ch = 0; ch < 2; ++ch){
      float a2[4][4];
      #pragma unroll
      for (int j = 0; j < 4; ++j)
        #pragma unroll
        for (int i = 0; i < 4; ++i) a2[j][i] = 0.f;
      #pragma unroll 4
      for (int k = 0; k < 64; ++k){
        const float4 w4 = *(const float4*)&Wp[k*128 + ch*64 + c0];
        #pragma unroll
        for (int j = 0; j < 4; ++j){
          const float a = sA[r0+j][k];
          a2[j][0] = fmaf(a, w4.x, a2[j][0]);
          a2[j][1] = fmaf(a, w4.y, a2[j][1]);
          a2[j][2] = fmaf(a, w4.z, a2[j][2]);
          a2[j][3] = fmaf(a, w4.w, a2[j][3]);
        }
      }
      // permuted column base: logical cbase = ch*64 + c0 (4-aligned)
      const int cbase = ch*64 + c0;
      const int kt = cbase >> 4, kgp = (cbase >> 2) & 3;
      const int pbase = kgp*32 + kt*4;
      #pragma unroll
      for (int j = 0; j < 4; ++j){
        int n = n0 + r0 + j;
        if (n < NN){
          half4 v;
          #pragma unroll
          for (int i = 0; i < 4; ++i) v[i] = (_Float16)a2[j][i];
          *(half4*)&dstp[(size_t)n*128 + pbase] = v;
        }
      }
    }
  }
}

// Edge MLP v8: 4 tiles/block, register prefetch pipeline, k-permuted contiguous
// fragment gathers, B hoisted, block-segmented reduce. 2 barriers/tile.
__global__ __launch_bounds__(256) void edge_mlp8(
    const u64* __restrict__ sd,
    const _Float16* __restrict__ Pp, const _Float16* __restrict__ Qp,
    const _Float16* __restrict__ b1h,
    const _Float16* __restrict__ w2t, const _Float16* __restrict__ w2gh,
    const float* __restrict__ b2,
    float* __restrict__ nfoc1, unsigned* __restrict__ nfoc2)
{
  __shared__ _Float16 sA[64][136];     // mid' (k-permuted), single buffer
  __shared__ _Float16 sOutH[64][136];  // raw o+bias (f16)
  __shared__ float sK[2][64];
  __shared__ int   sD[2][64];
  const int t = threadIdx.x;
  const int lane = t & 63, wv = t >> 6;
  const int r  = lane & 15;     // A-row / B-col / D-col
  const int kg = lane >> 4;     // k-group / D-row-quad
  const int row0 = wv * 16;
  const int base = blockIdx.x * 256;   // 4 tiles x 64 edges

  // hoist B-fragments for this wave's 2 col-tiles (contiguous 64B per col,kg)
  const int ct0 = wv * 2;
  half4 bf0[8], bf1[8];
  float bias0, bias1;
  {
    const int col0 = ct0*16 + r, col1 = (ct0+1)*16 + r;
    bias0 = b2[1 + col0]; bias1 = b2[1 + col1];
    const _Float16* w0p = &w2t[(size_t)col0*128 + kg*32];
    const _Float16* w1p = &w2t[(size_t)col1*128 + kg*32];
    #pragma unroll
    for (int kt = 0; kt < 8; ++kt){
      bf0[kt] = *(const half4*)&w0p[kt*4];
      bf1[kt] = *(const half4*)&w1p[kt*4];
    }
  }
  const float gb = b2[0];

#define LOADRAW(PH, QH, SS, DD, TILE) { \
    const u64 sdv = sd[base + (TILE)*64 + row0 + r]; \
    SS = (int)(unsigned)(sdv & 0xffffffffu); \
    DD = (int)(unsigned)(sdv >> 32); \
    const _Float16* pr = &Pp[(size_t)SS * 128 + kg*32]; \
    const _Float16* qr = &Qp[(size_t)DD * 128 + kg*32]; \
    PH[0] = *(const half8*)&pr[0];  PH[1] = *(const half8*)&pr[8]; \
    PH[2] = *(const half8*)&pr[16]; PH[3] = *(const half8*)&pr[24]; \
    QH[0] = *(const half8*)&qr[0];  QH[1] = *(const half8*)&qr[8]; \
    QH[2] = *(const half8*)&qr[16]; QH[3] = *(const half8*)&qr[24]; }

#define PROCESS(PH, QH, DD, BUF) { \
    if (kg == 0) sD[BUF][row0 + r] = DD; \
    float gp = 0.f; \
    _Pragma("unroll") \
    for (int i = 0; i < 4; ++i){ \
      const half8 b1v = *(const half8*)&b1h[kg*32 + i*8]; \
      const half8 wgv = *(const half8*)&w2gh[kg*32 + i*8]; \
      half8 mh; \
      _Pragma("unroll") \
      for (int j = 0; j < 8; ++j){ \
        float v = lrelu((float)PH[i][j] + (float)QH[i][j] + (float)b1v[j]); \
        gp = fmaf(v, (float)wgv[j], gp); \
        mh[j] = (_Float16)v; \
      } \
      *(half8*)&sA[row0 + r][kg*32 + i*8] = mh; \
    } \
    gp += __shfl_xor(gp, 16); \
    gp += __shfl_xor(gp, 32); \
    if (kg == 0) sK[BUF][row0 + r] = 1.f / (1.f + expf(-(gp + gb))); }

#define COMPUTE() { \
    _Pragma("unroll") \
    for (int rt = 0; rt < 4; ++rt){ \
      half4 af[8]; \
      const _Float16* ar = &sA[rt*16 + r][kg*32]; \
      _Pragma("unroll") \
      for (int kt = 0; kt < 8; ++kt) af[kt] = *(const half4*)&ar[kt*4]; \
      f32x4 a0 = {0.f,0.f,0.f,0.f}, a1 = {0.f,0.f,0.f,0.f}; \
      _Pragma("unroll") \
      for (int kt = 0; kt < 8; ++kt){ \
        a0 = __builtin_amdgcn_mfma_f32_16x16x16f16(af[kt], bf0[kt], a0, 0, 0, 0); \
        a1 = __builtin_amdgcn_mfma_f32_16x16x16f16(af[kt], bf1[kt], a1, 0, 0, 0); \
      } \
      _Pragma("unroll") \
      for (int reg = 0; reg < 4; ++reg){ \
        const int row = rt*16 + kg*4 + reg; \
        sOutH[row][ ct0   *16 + r] = (_Float16)(a0[reg] + bias0); \
        sOutH[row][(ct0+1)*16 + r] = (_Float16)(a1[reg] + bias1); \
      } \
    } }

#define REDUCE(BUF) { \
    const int c = t & 127; \
    const int rbeg = (t >> 7) * 32; \
    const bool isSum = c < 64; \
    float acc = isSum ? 0.f : -1e30f; \
    int curd = sD[BUF][rbeg]; \
    _Pragma("unroll 4") \
    for (int rw = rbeg; rw < rbeg + 32; ++rw){ \
      const float v = (float)sOutH[rw][c] * sK[BUF][rw]; \
      acc = isSum ? (acc + v) : fmaxf(acc, v); \
      const bool last = (rw == rbeg + 31) || (sD[BUF][rw + 1] != curd); \
      if (last){ \
        if (isSum){ \
          unsafeAtomicAdd(&nfoc1[(size_t)curd*64 + c], acc); \
          acc = 0.f; \
        } else { \
          atomicMax(&nfoc2[(size_t)curd*64 + (c - 64)], fenc(acc)); \
          acc = -1e30f; \
        } \
        if (rw < rbeg + 31) curd = sD[BUF][rw + 1]; \
      } \
    } }

  int s0, d0, s1, d1;
  half8 ph0[4], qh0[4], ph1[4], qh1[4];

  LOADRAW(ph0, qh0, s0, d0, 0);

  // tile 0
  LOADRAW(ph1, qh1, s1, d1, 1);
  PROCESS(ph0, qh0, d0, 0);
  __syncthreads();
  COMPUTE();
  __syncthreads();
  REDUCE(0);

  // tile 1
  LOADRAW(ph0, qh0, s0, d0, 2);
  PROCESS(ph1, qh1, d1, 1);
  __syncthreads();
  COMPUTE();
  __syncthreads();
  REDUCE(1);

  // tile 2
  LOADRAW(ph1, qh1, s1, d1, 3);
  PROCESS(ph0, qh0, d0, 0);
  __syncthreads();
  COMPUTE();
  __syncthreads();
  REDUCE(0);

  // tile 3
  PROCESS(ph1, qh1, d1, 1);
  __syncthreads();
  COMPUTE();
  __syncthreads();
  REDUCE(1);

#undef LOADRAW
#undef PROCESS
#undef COMPUTE
#undef REDUCE
}

// Node-side post: new_x = concat(x,nfoc1,dec(nfoc2))@red_w+red_b; out += new_x@l2w+l2b
__global__ __launch_bounds__(256) void node_post(
    const float* __restrict__ x, const float* __restrict__ nfoc1,
    const unsigned* __restrict__ nfoc2, const unsigned* __restrict__ counts,
    const float* __restrict__ redw, const float* __restrict__ redb,
    const float* __restrict__ l2w, const float* __restrict__ l2b,
    float* __restrict__ out)
{
  __shared__ float sC[64][197];
  __shared__ float sN[64][65];
  const int t = threadIdx.x;
  const int n0 = blockIdx.x * 64;
  const int rr = t >> 4, c4 = (t & 15) * 4;

  #pragma unroll
  for (int i = 0; i < 4; ++i){
    int r = rr + i*16, n = n0 + r;
    float4 xv = make_float4(0,0,0,0), f1 = make_float4(0,0,0,0);
    uint4 f2 = make_uint4(0,0,0,0);
    bool has = false;
    if (n < NN){
      xv = *(const float4*)&x[(size_t)n*64 + c4];
      f1 = *(const float4*)&nfoc1[(size_t)n*64 + c4];
      f2 = *(const uint4*)&nfoc2[(size_t)n*64 + c4];
      has = counts[n] > 0u;
    }
    sC[r][c4+0]=xv.x; sC[r][c4+1]=xv.y; sC[r][c4+2]=xv.z; sC[r][c4+3]=xv.w;
    sC[r][64+c4+0]=f1.x; sC[r][64+c4+1]=f1.y; sC[r][64+c4+2]=f1.z; sC[r][64+c4+3]=f1.w;
    sC[r][128+c4+0] = has ? fdec(f2.x) : 0.f;
    sC[r][128+c4+1] = has ? fdec(f2.y) : 0.f;
    sC[r][128+c4+2] = has ? fdec(f2.z) : 0.f;
    sC[r][128+c4+3] = has ? fdec(f2.w) : 0.f;
  }
  __syncthreads();

  const int c0 = (t & 15) * 4, r0 = (t >> 4) * 4;
  float acc[4][4];

  {
    const float4 b4 = *(const float4*)&redb[c0];
    #pragma unroll
    for (int j = 0; j < 4; ++j){ acc[j][0]=b4.x; acc[j][1]=b4.y; acc[j][2]=b4.z; acc[j][3]=b4.w; }
    #pragma unroll 4
    for (int k = 0; k < 192; ++k){
      const float4 w4 = *(const float4*)&redw[k*64 + c0];
      #pragma unroll
      for (int j = 0; j < 4; ++j){
        const float a = sC[r0+j][k];
        acc[j][0] = fmaf(a, w4.x, acc[j][0]);
        acc[j][1] = fmaf(a, w4.y, acc[j][1]);
        acc[j][2] = fmaf(a, w4.z, acc[j][2]);
        acc[j][3] = fmaf(a, w4.w, acc[j][3]);
      }
    }
    #pragma unroll
    for (int j = 0; j < 4; ++j)
      #pragma unroll
      for (int i = 0; i < 4; ++i) sN[r0+j][c0+i] = acc[j][i];
  }
  __syncthreads();

  gemm64(sN, l2w, l2b, t, acc);
  #pragma unroll
  for (int j = 0; j < 4; ++j){
    int n = n0 + r0 + j;
    if (n < NN){
      float4 cur = *(const float4*)&out[(size_t)n*64 + c0];
      cur.x += acc[j][0]; cur.y += acc[j][1]; cur.z += acc[j][2]; cur.w += acc[j][3];
      *(float4*)&out[(size_t)n*64 + c0] = cur;
    }
  }
}

extern "C" void kernel_launch(void* const* d_in, const int* in_sizes, int n_in,
                              void* d_out, int out_size, void* d_ws, size_t ws_size,
                              hipStream_t stream)
{
  const float* nf   = (const float*)d_in[0];
  const int*   src  = (const int*)d_in[1];
  const int*   dst  = (const int*)d_in[2];
  const float* rw1  = (const float*)d_in[3];
  const float* rb1  = (const float*)d_in[4];
  const float* rw2  = (const float*)d_in[5];
  const float* rb2  = (const float*)d_in[6];
  const float* l1w  = (const float*)d_in[7];
  const float* l1b  = (const float*)d_in[8];
  const float* l2w  = (const float*)d_in[9];
  const float* l2b  = (const float*)d_in[10];
  const float* mw1  = (const float*)d_in[11];
  const float* mb1  = (const float*)d_in[12];
  const float* mw2  = (const float*)d_in[13];
  const float* mb2  = (const float*)d_in[14];
  const float* redw = (const float*)d_in[15];
  const float* redb = (const float*)d_in[16];

  float* ws = (float*)d_ws;
  float*     x      = ws + XOFF;
  _Float16*  P      = (_Float16*)(ws + POFF);
  _Float16*  Q      = (_Float16*)(ws + QOFF);
  float*     nfoc1  = ws + N1OFF;
  unsigned*  nfoc2  = (unsigned*)(ws + N2OFF);
  _Float16*  w2t    = (_Float16*)(ws + W2TOFF);
  _Float16*  b1h    = (_Float16*)(ws + B1HOFF);
  _Float16*  w2gh   = (_Float16*)(ws + WGHOFF);
  unsigned*  counts = (unsigned*)(ws + CNTOFF);
  unsigned*  cursor = (unsigned*)(ws + CUROFF);
  unsigned*  partial= (unsigned*)(ws + PARTOFF);
  u64*       sdbuf  = (u64*)(ws + SDOFF);
  float*     out    = (float*)d_out;

  // zero: counts, and the contiguous nfoc1+nfoc2 region (0u == -inf sentinel for fenc)
  hipMemsetAsync(counts, 0, NN * sizeof(unsigned), stream);
  hipMemsetAsync(nfoc1, 0, (size_t)NN * 64 * 2 * sizeof(float), stream);
  hipLaunchKernelGGL(prep_k, dim3(65 + 3125), dim3(256), 0, stream,
                     mw2, mb1, w2t, b1h, w2gh, dst, counts);
  hipLaunchKernelGGL(scanA, dim3(196), dim3(256), 0, stream, counts, partial);
  hipLaunchKernelGGL(scanB, dim3(1),   dim3(256), 0, stream, partial, 196);
  hipLaunchKernelGGL(scanC, dim3(196), dim3(256), 0, stream, counts, partial, cursor);
  hipLaunchKernelGGL(assign_k, dim3(3125), dim3(256), 0, stream, src, dst, cursor, sdbuf);
  hipLaunchKernelGGL(node_pre, dim3(782), dim3(256), 0, stream,
                     nf, rw1, rb1, rw2, rb2, l1w, l1b, mw1, x, P, Q, out);
  hipLaunchKernelGGL(edge_mlp8, dim3(3125), dim3(256), 0, stream,
                     sdbuf, P, Q, b1h, w2t, w2gh, mb2, nfoc1, nfoc2);
  hipLaunchKernelGGL(node_post, dim3(782), dim3(256), 0, stream,
                     x, nfoc1, nfoc2, counts, redw, redb, l2w, l2b, out);
}

// Round 10
// 329.134 us; speedup vs baseline: 1.9931x; 1.1747x over previous
//
#include <hip/hip_runtime.h>

#define NN 50000
#define NE 800000

typedef _Float16 half8 __attribute__((ext_vector_type(8)));
typedef _Float16 half4 __attribute__((ext_vector_type(4)));
typedef float f32x4 __attribute__((ext_vector_type(4)));
typedef unsigned long long u64;

// ws layout (float offsets)
static const size_t XOFF   = 0;          // x      [50000*64] f32
static const size_t POFF   = 3200000;    // P(+b1) [50000*128] f16 (k-permuted)
static const size_t QOFF   = 6400000;    // Q      [50000*128] f16 (k-permuted)
static const size_t N1OFF  = 9600000;    // nfoc1  [50000*64] f32
static const size_t N2OFF  = 12800000;   // nfoc2  [50000*64] u32 (monotonic-encoded)
static const size_t W2TOFF = 16000000;   // w2t    [128c][128k'] f16 (col-major, k-perm)
static const size_t WGHOFF = 16008192;   // w2gh   [128] f16 (k-perm)
static const size_t RW1HOFF= 16008256;   // rw1h   [64c][64k] f16
static const size_t RW2HOFF= 16010304;   // rw2h   [64c][64k] f16
static const size_t L1WHOFF= 16012352;   // l1wh   [64c][64k] f16
static const size_t PWHOFF = 16014400;   // pwh    [128c][64k] f16
static const size_t QWHOFF = 16018496;   // qwh    [128c][64k] f16
static const size_t CNTOFF = 16022592;   // counts [50000] u32
static const size_t CUROFF = 16072592;   // cursor [50000] u32
static const size_t PARTOFF= 16122592;   // partial[256] u32
static const size_t SDOFF  = 16122848;   // sdbuf  [800000] u64

__device__ __forceinline__ unsigned fenc(float f){
  unsigned b = __float_as_uint(f);
  return (b & 0x80000000u) ? ~b : (b | 0x80000000u);
}
__device__ __forceinline__ float fdec(unsigned u){
  return (u & 0x80000000u) ? __uint_as_float(u & 0x7fffffffu) : __uint_as_float(~u);
}

// 64x64 tile GEMM (fp32 VALU) — still used by node_post
__device__ __forceinline__ void gemm64(const float (*sIn)[65], const float* __restrict__ W,
                                       const float* __restrict__ bias, int t, float acc[4][4])
{
  const int c0 = (t & 15) * 4, r0 = (t >> 4) * 4;
  const float4 b4 = *(const float4*)&bias[c0];
  #pragma unroll
  for (int j = 0; j < 4; ++j){ acc[j][0]=b4.x; acc[j][1]=b4.y; acc[j][2]=b4.z; acc[j][3]=b4.w; }
  #pragma unroll 4
  for (int k = 0; k < 64; ++k){
    const float4 w4 = *(const float4*)&W[k*64 + c0];
    #pragma unroll
    for (int j = 0; j < 4; ++j){
      const float a = sIn[r0+j][k];
      acc[j][0] = fmaf(a, w4.x, acc[j][0]);
      acc[j][1] = fmaf(a, w4.y, acc[j][1]);
      acc[j][2] = fmaf(a, w4.z, acc[j][2]);
      acc[j][3] = fmaf(a, w4.w, acc[j][3]);
    }
  }
}

// k-permutation: k' = kg*32 + kt*4 + j  <->  k = kt*16 + kg*4 + j
__device__ __forceinline__ int kperm(int kp){
  const int kg = kp >> 5, rem = kp & 31, kt = rem >> 2, j = rem & 3;
  return kt*16 + kg*4 + j;
}

// blocks 0..176: weight relayouts/conversions. blocks 177+: dst histogram.
__global__ __launch_bounds__(256) void prep_k(
    const float* __restrict__ w2, const float* __restrict__ rw1,
    const float* __restrict__ rw2, const float* __restrict__ l1w,
    const float* __restrict__ mw1,
    _Float16* __restrict__ w2t, _Float16* __restrict__ w2gh,
    _Float16* __restrict__ rw1h, _Float16* __restrict__ rw2h,
    _Float16* __restrict__ l1wh, _Float16* __restrict__ pwh,
    _Float16* __restrict__ qwh,
    const int* __restrict__ dst, unsigned* __restrict__ counts)
{
  const int b = blockIdx.x;
  if (b < 177){
    int i = b * 256 + threadIdx.x;
    if (i < 16384){
      int c = i >> 7, kp = i & 127;
      w2t[i] = (_Float16)w2[kperm(kp)*129 + 1 + c];
    } else if (i < 16512){
      int kp = i - 16384;
      w2gh[kp] = (_Float16)w2[kperm(kp)*129];
    } else if (i < 20608){
      int idx = i - 16512, c = idx >> 6, k = idx & 63;
      rw1h[idx] = (_Float16)rw1[k*64 + c];
    } else if (i < 24704){
      int idx = i - 20608, c = idx >> 6, k = idx & 63;
      rw2h[idx] = (_Float16)rw2[k*64 + c];
    } else if (i < 28800){
      int idx = i - 24704, c = idx >> 6, k = idx & 63;
      l1wh[idx] = (_Float16)l1w[k*64 + c];
    } else if (i < 36992){
      int idx = i - 28800, c = idx >> 6, k = idx & 63;
      pwh[idx] = (_Float16)mw1[k*128 + c];
    } else if (i < 45184){
      int idx = i - 36992, c = idx >> 6, k = idx & 63;
      qwh[idx] = (_Float16)mw1[(64 + k)*128 + c];
    }
  } else {
    int e = (b - 177) * 256 + threadIdx.x;
    if (e < NE) atomicAdd(&counts[dst[e]], 1u);
  }
}

// per-block sums of counts -> partial[196]
__global__ __launch_bounds__(256) void scanA(const unsigned* __restrict__ counts,
                                             unsigned* __restrict__ partial)
{
  __shared__ unsigned s[256];
  const int t = threadIdx.x;
  const int idx = blockIdx.x * 256 + t;
  s[t] = (idx < NN) ? counts[idx] : 0u;
  __syncthreads();
  for (int d = 128; d > 0; d >>= 1){
    if (t < d) s[t] += s[t + d];
    __syncthreads();
  }
  if (t == 0) partial[blockIdx.x] = s[0];
}

__global__ __launch_bounds__(256) void scanB(unsigned* __restrict__ partial, int nb)
{
  __shared__ unsigned s[256];
  const int t = threadIdx.x;
  unsigned v = (t < nb) ? partial[t] : 0u;
  s[t] = v;
  __syncthreads();
  for (int d = 1; d < 256; d <<= 1){
    unsigned u = (t >= d) ? s[t - d] : 0u;
    __syncthreads();
    s[t] += u;
    __syncthreads();
  }
  if (t < nb) partial[t] = s[t] - v;   // exclusive
}

__global__ __launch_bounds__(256) void scanC(const unsigned* __restrict__ counts,
                                             const unsigned* __restrict__ partial,
                                             unsigned* __restrict__ cursor)
{
  __shared__ unsigned s[256];
  const int t = threadIdx.x;
  const int idx = blockIdx.x * 256 + t;
  unsigned v = (idx < NN) ? counts[idx] : 0u;
  s[t] = v;
  __syncthreads();
  for (int d = 1; d < 256; d <<= 1){
    unsigned u = (t >= d) ? s[t - d] : 0u;
    __syncthreads();
    s[t] += u;
    __syncthreads();
  }
  if (idx < NN) cursor[idx] = partial[blockIdx.x] + s[t] - v;
}

// slot assignment: sdbuf[slot] = (dst<<32)|src, slots grouped by dst
__global__ __launch_bounds__(256) void assign_k(const int* __restrict__ src,
                                                const int* __restrict__ dst,
                                                unsigned* __restrict__ cursor,
                                                u64* __restrict__ sdbuf)
{
  int e = blockIdx.x * 256 + threadIdx.x;
  if (e < NE){
    const int d = dst[e];
    unsigned slot = atomicAdd(&cursor[d], 1u);
    sdbuf[slot] = ((u64)(unsigned)d << 32) | (unsigned)src[e];
  }
}

// Node-side precompute, MFMA version. 64 nodes/block, 4 waves; wave wv owns
// col-tile wv for the 64-col GEMMs and col-tiles {wv, wv+4} of P and Q.
__global__ __launch_bounds__(256) void node_pre_m(
    const float* __restrict__ nf,
    const _Float16* __restrict__ rw1h, const float* __restrict__ rb1,
    const _Float16* __restrict__ rw2h, const float* __restrict__ rb2,
    const _Float16* __restrict__ l1wh, const float* __restrict__ l1b,
    const _Float16* __restrict__ pwh, const _Float16* __restrict__ qwh,
    const float* __restrict__ mb1,
    float* __restrict__ x_out, _Float16* __restrict__ Pp, _Float16* __restrict__ Qp,
    float* __restrict__ out)
{
  __shared__ _Float16 sM[64][72];   // nf -> (after GEMM2) x, f16
  __shared__ _Float16 sT[64][72];   // tmp
  const int t = threadIdx.x;
  const int lane = t & 63, wv = t >> 6;
  const int l15 = lane & 15, kg = lane >> 4;
  const int n0 = blockIdx.x * 64;

  // stage nf tile -> f16 sM (coalesced float4 reads)
  {
    const int rr = t >> 4, c4 = (t & 15) * 4;
    #pragma unroll
    for (int i = 0; i < 4; ++i){
      int r = rr + i*16, n = n0 + r;
      float4 v = make_float4(0.f,0.f,0.f,0.f);
      if (n < NN) v = *(const float4*)&nf[(size_t)n*64 + c4];
      half4 h; h[0]=(_Float16)v.x; h[1]=(_Float16)v.y; h[2]=(_Float16)v.z; h[3]=(_Float16)v.w;
      *(half4*)&sM[r][c4] = h;
    }
  }
  __syncthreads();

  const int col = wv*16 + l15;

  // GEMM1: tmp = nf@rw1 + rb1 -> sT
  {
    half4 bf[4];
    #pragma unroll
    for (int kt = 0; kt < 4; ++kt) bf[kt] = *(const half4*)&rw1h[col*64 + kt*16 + kg*4];
    const float bias = rb1[col];
    #pragma unroll
    for (int rt = 0; rt < 4; ++rt){
      f32x4 acc = {0.f,0.f,0.f,0.f};
      #pragma unroll
      for (int kt = 0; kt < 4; ++kt){
        const half4 af = *(const half4*)&sM[rt*16 + l15][kt*16 + kg*4];
        acc = __builtin_amdgcn_mfma_f32_16x16x16f16(af, bf[kt], acc, 0, 0, 0);
      }
      #pragma unroll
      for (int reg = 0; reg < 4; ++reg)
        sT[rt*16 + kg*4 + reg][col] = (_Float16)(acc[reg] + bias);
    }
  }
  __syncthreads();

  // GEMM2: x = tmp@rw2 + rb2 + nf -> x_out (f32) and sM (f16, in-place; each
  // element read+written only by its owning lane)
  {
    half4 bf[4];
    #pragma unroll
    for (int kt = 0; kt < 4; ++kt) bf[kt] = *(const half4*)&rw2h[col*64 + kt*16 + kg*4];
    const float bias = rb2[col];
    #pragma unroll
    for (int rt = 0; rt < 4; ++rt){
      f32x4 acc = {0.f,0.f,0.f,0.f};
      #pragma unroll
      for (int kt = 0; kt < 4; ++kt){
        const half4 af = *(const half4*)&sT[rt*16 + l15][kt*16 + kg*4];
        acc = __builtin_amdgcn_mfma_f32_16x16x16f16(af, bf[kt], acc, 0, 0, 0);
      }
      #pragma unroll
      for (int reg = 0; reg < 4; ++reg){
        const int row = rt*16 + kg*4 + reg;
        const float xv = acc[reg] + bias + (float)sM[row][col];
        const int n = n0 + row;
        if (n < NN) x_out[(size_t)n*64 + col] = xv;
        sM[row][col] = (_Float16)xv;
      }
    }
  }
  __syncthreads();

  // GEMM3: x1 = x@l1w + l1b -> out
  {
    half4 bf[4];
    #pragma unroll
    for (int kt = 0; kt < 4; ++kt) bf[kt] = *(const half4*)&l1wh[col*64 + kt*16 + kg*4];
    const float bias = l1b[col];
    #pragma unroll
    for (int rt = 0; rt < 4; ++rt){
      f32x4 acc = {0.f,0.f,0.f,0.f};
      #pragma unroll
      for (int kt = 0; kt < 4; ++kt){
        const half4 af = *(const half4*)&sM[rt*16 + l15][kt*16 + kg*4];
        acc = __builtin_amdgcn_mfma_f32_16x16x16f16(af, bf[kt], acc, 0, 0, 0);
      }
      #pragma unroll
      for (int reg = 0; reg < 4; ++reg){
        const int row = rt*16 + kg*4 + reg;
        const int n = n0 + row;
        if (n < NN) out[(size_t)n*64 + col] = acc[reg] + bias;
      }
    }
  }

  // GEMM4/5: P = x@W1top + b1 (bias folded), Q = x@W1bot; k-permuted stores
  #pragma unroll
  for (int g = 0; g < 2; ++g){
    const _Float16* WH = g ? qwh : pwh;
    _Float16* dstp = g ? Qp : Pp;
    #pragma unroll
    for (int h = 0; h < 2; ++h){
      const int ct = h*4 + wv;
      const int colp = ct*16 + l15;
      half4 bf[4];
      #pragma unroll
      for (int kt = 0; kt < 4; ++kt) bf[kt] = *(const half4*)&WH[colp*64 + kt*16 + kg*4];
      const float bias = g ? 0.f : mb1[colp];
      const int kgc = l15 >> 2, jj = l15 & 3;
      const int pos = kgc*32 + ct*4 + jj;   // kperm(pos) == colp
      #pragma unroll
      for (int rt = 0; rt < 4; ++rt){
        f32x4 acc = {0.f,0.f,0.f,0.f};
        #pragma unroll
        for (int kt = 0; kt < 4; ++kt){
          const half4 af = *(const half4*)&sM[rt*16 + l15][kt*16 + kg*4];
          acc = __builtin_amdgcn_mfma_f32_16x16x16f16(af, bf[kt], acc, 0, 0, 0);
        }
        #pragma unroll
        for (int reg = 0; reg < 4; ++reg){
          const int row = rt*16 + kg*4 + reg;
          const int n = n0 + row;
          if (n < NN) dstp[(size_t)n*128 + pos] = (_Float16)(acc[reg] + bias);
        }
      }
    }
  }
}

// Edge MLP v8b: 4 tiles/block, register prefetch pipeline, packed-f16 lrelu,
// b1 pre-folded into P, B + gate weights hoisted. 2 barriers/tile.
__global__ __launch_bounds__(256) void edge_mlp8(
    const u64* __restrict__ sd,
    const _Float16* __restrict__ Pp, const _Float16* __restrict__ Qp,
    const _Float16* __restrict__ w2t, const _Float16* __restrict__ w2gh,
    const float* __restrict__ b2,
    float* __restrict__ nfoc1, unsigned* __restrict__ nfoc2)
{
  __shared__ _Float16 sA[64][136];     // mid' (k-permuted), single buffer
  __shared__ _Float16 sOutH[64][136];  // raw o+bias (f16)
  __shared__ float sK[2][64];
  __shared__ int   sD[2][64];
  const int t = threadIdx.x;
  const int lane = t & 63, wv = t >> 6;
  const int r  = lane & 15;
  const int kg = lane >> 4;
  const int row0 = wv * 16;
  const int base = blockIdx.x * 256;

  // hoist B-fragments (2 col-tiles) + gate weights
  const int ct0 = wv * 2;
  half4 bf0[8], bf1[8];
  half8 wgr[4];
  float bias0, bias1;
  {
    const int col0 = ct0*16 + r, col1 = (ct0+1)*16 + r;
    bias0 = b2[1 + col0]; bias1 = b2[1 + col1];
    const _Float16* w0p = &w2t[(size_t)col0*128 + kg*32];
    const _Float16* w1p = &w2t[(size_t)col1*128 + kg*32];
    #pragma unroll
    for (int kt = 0; kt < 8; ++kt){
      bf0[kt] = *(const half4*)&w0p[kt*4];
      bf1[kt] = *(const half4*)&w1p[kt*4];
    }
    #pragma unroll
    for (int i = 0; i < 4; ++i) wgr[i] = *(const half8*)&w2gh[kg*32 + i*8];
  }
  const float gb = b2[0];

#define LOADRAW(PH, QH, SS, DD, TILE) { \
    const u64 sdv = sd[base + (TILE)*64 + row0 + r]; \
    SS = (int)(unsigned)(sdv & 0xffffffffu); \
    DD = (int)(unsigned)(sdv >> 32); \
    const _Float16* pr = &Pp[(size_t)SS * 128 + kg*32]; \
    const _Float16* qr = &Qp[(size_t)DD * 128 + kg*32]; \
    PH[0] = *(const half8*)&pr[0];  PH[1] = *(const half8*)&pr[8]; \
    PH[2] = *(const half8*)&pr[16]; PH[3] = *(const half8*)&pr[24]; \
    QH[0] = *(const half8*)&qr[0];  QH[1] = *(const half8*)&qr[8]; \
    QH[2] = *(const half8*)&qr[16]; QH[3] = *(const half8*)&qr[24]; }

#define PROCESS(PH, QH, DD, BUF) { \
    if (kg == 0) sD[BUF][row0 + r] = DD; \
    float gp = 0.f; \
    _Pragma("unroll") \
    for (int i = 0; i < 4; ++i){ \
      half8 mv = PH[i] + QH[i]; \
      const half8 m2 = mv * (_Float16)0.2f; \
      mv = __builtin_elementwise_max(mv, m2); \
      _Pragma("unroll") \
      for (int j = 0; j < 8; ++j) \
        gp = fmaf((float)mv[j], (float)wgr[i][j], gp); \
      *(half8*)&sA[row0 + r][kg*32 + i*8] = mv; \
    } \
    gp += __shfl_xor(gp, 16); \
    gp += __shfl_xor(gp, 32); \
    if (kg == 0) sK[BUF][row0 + r] = 1.f / (1.f + expf(-(gp + gb))); }

#define COMPUTE() { \
    _Pragma("unroll") \
    for (int rt = 0; rt < 4; ++rt){ \
      half4 af[8]; \
      const _Float16* ar = &sA[rt*16 + r][kg*32]; \
      _Pragma("unroll") \
      for (int kt = 0; kt < 8; ++kt) af[kt] = *(const half4*)&ar[kt*4]; \
      f32x4 a0 = {0.f,0.f,0.f,0.f}, a1 = {0.f,0.f,0.f,0.f}; \
      _Pragma("unroll") \
      for (int kt = 0; kt < 8; ++kt){ \
        a0 = __builtin_amdgcn_mfma_f32_16x16x16f16(af[kt], bf0[kt], a0, 0, 0, 0); \
        a1 = __builtin_amdgcn_mfma_f32_16x16x16f16(af[kt], bf1[kt], a1, 0, 0, 0); \
      } \
      _Pragma("unroll") \
      for (int reg = 0; reg < 4; ++reg){ \
        const int row = rt*16 + kg*4 + reg; \
        sOutH[row][ ct0   *16 + r] = (_Float16)(a0[reg] + bias0); \
        sOutH[row][(ct0+1)*16 + r] = (_Float16)(a1[reg] + bias1); \
      } \
    } }

#define REDUCE(BUF) { \
    const int c = t & 127; \
    const int rbeg = (t >> 7) * 32; \
    const bool isSum = c < 64; \
    float acc = isSum ? 0.f : -1e30f; \
    int curd = sD[BUF][rbeg]; \
    _Pragma("unroll 4") \
    for (int rw = rbeg; rw < rbeg + 32; ++rw){ \
      const float v = (float)sOutH[rw][c] * sK[BUF][rw]; \
      acc = isSum ? (acc + v) : fmaxf(acc, v); \
      const bool last = (rw == rbeg + 31) || (sD[BUF][rw + 1] != curd); \
      if (last){ \
        if (isSum){ \
          unsafeAtomicAdd(&nfoc1[(size_t)curd*64 + c], acc); \
          acc = 0.f; \
        } else { \
          atomicMax(&nfoc2[(size_t)curd*64 + (c - 64)], fenc(acc)); \
          acc = -1e30f; \
        } \
        if (rw < rbeg + 31) curd = sD[BUF][rw + 1]; \
      } \
    } }

  int s0, d0, s1, d1;
  half8 ph0[4], qh0[4], ph1[4], qh1[4];

  LOADRAW(ph0, qh0, s0, d0, 0);

  // tile 0
  LOADRAW(ph1, qh1, s1, d1, 1);
  PROCESS(ph0, qh0, d0, 0);
  __syncthreads();
  COMPUTE();
  __syncthreads();
  REDUCE(0);

  // tile 1
  LOADRAW(ph0, qh0, s0, d0, 2);
  PROCESS(ph1, qh1, d1, 1);
  __syncthreads();
  COMPUTE();
  __syncthreads();
  REDUCE(1);

  // tile 2
  LOADRAW(ph1, qh1, s1, d1, 3);
  PROCESS(ph0, qh0, d0, 0);
  __syncthreads();
  COMPUTE();
  __syncthreads();
  REDUCE(0);

  // tile 3
  PROCESS(ph1, qh1, d1, 1);
  __syncthreads();
  COMPUTE();
  __syncthreads();
  REDUCE(1);

#undef LOADRAW
#undef PROCESS
#undef COMPUTE
#undef REDUCE
}

// Node-side post: new_x = concat(x,nfoc1,dec(nfoc2))@red_w+red_b; out += new_x@l2w+l2b
__global__ __launch_bounds__(256) void node_post(
    const float* __restrict__ x, const float* __restrict__ nfoc1,
    const unsigned* __restrict__ nfoc2, const unsigned* __restrict__ counts,
    const float* __restrict__ redw, const float* __restrict__ redb,
    const float* __restrict__ l2w, const float* __restrict__ l2b,
    float* __restrict__ out)
{
  __shared__ float sC[64][197];
  __shared__ float sN[64][65];
  const int t = threadIdx.x;
  const int n0 = blockIdx.x * 64;
  const int rr = t >> 4, c4 = (t & 15) * 4;

  #pragma unroll
  for (int i = 0; i < 4; ++i){
    int r = rr + i*16, n = n0 + r;
    float4 xv = make_float4(0,0,0,0), f1 = make_float4(0,0,0,0);
    uint4 f2 = make_uint4(0,0,0,0);
    bool has = false;
    if (n < NN){
      xv = *(const float4*)&x[(size_t)n*64 + c4];
      f1 = *(const float4*)&nfoc1[(size_t)n*64 + c4];
      f2 = *(const uint4*)&nfoc2[(size_t)n*64 + c4];
      has = counts[n] > 0u;
    }
    sC[r][c4+0]=xv.x; sC[r][c4+1]=xv.y; sC[r][c4+2]=xv.z; sC[r][c4+3]=xv.w;
    sC[r][64+c4+0]=f1.x; sC[r][64+c4+1]=f1.y; sC[r][64+c4+2]=f1.z; sC[r][64+c4+3]=f1.w;
    sC[r][128+c4+0] = has ? fdec(f2.x) : 0.f;
    sC[r][128+c4+1] = has ? fdec(f2.y) : 0.f;
    sC[r][128+c4+2] = has ? fdec(f2.z) : 0.f;
    sC[r][128+c4+3] = has ? fdec(f2.w) : 0.f;
  }
  __syncthreads();

  const int c0 = (t & 15) * 4, r0 = (t >> 4) * 4;
  float acc[4][4];

  {
    const float4 b4 = *(const float4*)&redb[c0];
    #pragma unroll
    for (int j = 0; j < 4; ++j){ acc[j][0]=b4.x; acc[j][1]=b4.y; acc[j][2]=b4.z; acc[j][3]=b4.w; }
    #pragma unroll 4
    for (int k = 0; k < 192; ++k){
      const float4 w4 = *(const float4*)&redw[k*64 + c0];
      #pragma unroll
      for (int j = 0; j < 4; ++j){
        const float a = sC[r0+j][k];
        acc[j][0] = fmaf(a, w4.x, acc[j][0]);
        acc[j][1] = fmaf(a, w4.y, acc[j][1]);
        acc[j][2] = fmaf(a, w4.z, acc[j][2]);
        acc[j][3] = fmaf(a, w4.w, acc[j][3]);
      }
    }
    #pragma unroll
    for (int j = 0; j < 4; ++j)
      #pragma unroll
      for (int i = 0; i < 4; ++i) sN[r0+j][c0+i] = acc[j][i];
  }
  __syncthreads();

  gemm64(sN, l2w, l2b, t, acc);
  #pragma unroll
  for (int j = 0; j < 4; ++j){
    int n = n0 + r0 + j;
    if (n < NN){
      float4 cur = *(const float4*)&out[(size_t)n*64 + c0];
      cur.x += acc[j][0]; cur.y += acc[j][1]; cur.z += acc[j][2]; cur.w += acc[j][3];
      *(float4*)&out[(size_t)n*64 + c0] = cur;
    }
  }
}

extern "C" void kernel_launch(void* const* d_in, const int* in_sizes, int n_in,
                              void* d_out, int out_size, void* d_ws, size_t ws_size,
                              hipStream_t stream)
{
  const float* nf   = (const float*)d_in[0];
  const int*   src  = (const int*)d_in[1];
  const int*   dst  = (const int*)d_in[2];
  const float* rw1  = (const float*)d_in[3];
  const float* rb1  = (const float*)d_in[4];
  const float* rw2  = (const float*)d_in[5];
  const float* rb2  = (const float*)d_in[6];
  const float* l1w  = (const float*)d_in[7];
  const float* l1b  = (const float*)d_in[8];
  const float* l2w  = (const float*)d_in[9];
  const float* l2b  = (const float*)d_in[10];
  const float* mw1  = (const float*)d_in[11];
  const float* mb1  = (const float*)d_in[12];
  const float* mw2  = (const float*)d_in[13];
  const float* mb2  = (const float*)d_in[14];
  const float* redw = (const float*)d_in[15];
  const float* redb = (const float*)d_in[16];

  float* ws = (float*)d_ws;
  float*     x      = ws + XOFF;
  _Float16*  P      = (_Float16*)(ws + POFF);
  _Float16*  Q      = (_Float16*)(ws + QOFF);
  float*     nfoc1  = ws + N1OFF;
  unsigned*  nfoc2  = (unsigned*)(ws + N2OFF);
  _Float16*  w2t    = (_Float16*)(ws + W2TOFF);
  _Float16*  w2gh   = (_Float16*)(ws + WGHOFF);
  _Float16*  rw1h   = (_Float16*)(ws + RW1HOFF);
  _Float16*  rw2h   = (_Float16*)(ws + RW2HOFF);
  _Float16*  l1wh   = (_Float16*)(ws + L1WHOFF);
  _Float16*  pwh    = (_Float16*)(ws + PWHOFF);
  _Float16*  qwh    = (_Float16*)(ws + QWHOFF);
  unsigned*  counts = (unsigned*)(ws + CNTOFF);
  unsigned*  cursor = (unsigned*)(ws + CUROFF);
  unsigned*  partial= (unsigned*)(ws + PARTOFF);
  u64*       sdbuf  = (u64*)(ws + SDOFF);
  float*     out    = (float*)d_out;

  hipMemsetAsync(counts, 0, NN * sizeof(unsigned), stream);
  hipMemsetAsync(nfoc1, 0, (size_t)NN * 64 * 2 * sizeof(float), stream);
  hipLaunchKernelGGL(prep_k, dim3(177 + 3125), dim3(256), 0, stream,
                     mw2, rw1, rw2, l1w, mw1,
                     w2t, w2gh, rw1h, rw2h, l1wh, pwh, qwh, dst, counts);
  hipLaunchKernelGGL(scanA, dim3(196), dim3(256), 0, stream, counts, partial);
  hipLaunchKernelGGL(scanB, dim3(1),   dim3(256), 0, stream, partial, 196);
  hipLaunchKernelGGL(scanC, dim3(196), dim3(256), 0, stream, counts, partial, cursor);
  hipLaunchKernelGGL(assign_k, dim3(3125), dim3(256), 0, stream, src, dst, cursor, sdbuf);
  hipLaunchKernelGGL(node_pre_m, dim3(782), dim3(256), 0, stream,
                     nf, rw1h, rb1, rw2h, rb2, l1wh, l1b, pwh, qwh, mb1,
                     x, P, Q, out);
  hipLaunchKernelGGL(edge_mlp8, dim3(3125), dim3(256), 0, stream,
                     sdbuf, P, Q, w2t, w2gh, mb2, nfoc1, nfoc2);
  hipLaunchKernelGGL(node_post, dim3(782), dim3(256), 0, stream,
                     x, nfoc1, nfoc2, counts, redw, redb, l2w, l2b, out);
}